// Round 2
// baseline (790.000 us; speedup 1.0000x reference)
//
#include <hip/hip_runtime.h>

#define FIN 256
#define H1 8
#define C1 16
#define D1 128   // H1*C1
#define D2 40

static __device__ __forceinline__ float lrelu(float x){ return fmaxf(x, 0.2f*x); }
static __device__ __forceinline__ float elu(float x){ return x > 0.f ? x : __expf(x) - 1.f; }

// ---------------- CSR build ----------------
__global__ void hist_k(const int* __restrict__ dst, int E, int* __restrict__ deg){
  int i = blockIdx.x*blockDim.x + threadIdx.x;
  if (i < E) atomicAdd(&deg[dst[i]], 1);
}

__global__ __launch_bounds__(1024) void scan_k(int* __restrict__ off, int* __restrict__ cursor, int N){
  __shared__ int sums[1024];
  int t = threadIdx.x;
  int CH = (N + 1023)/1024;
  int lo = t*CH; int hi = lo + CH;
  if (lo > N) lo = N;
  if (hi > N) hi = N;
  int s = 0;
  for (int i = lo; i < hi; ++i) s += off[i];
  sums[t] = s; __syncthreads();
  for (int o = 1; o < 1024; o <<= 1){
    int v = (t >= o) ? sums[t-o] : 0;
    __syncthreads();
    sums[t] += v;
    __syncthreads();
  }
  int run = (t == 0) ? 0 : sums[t-1];
  for (int i = lo; i < hi; ++i){
    int d = off[i];
    off[i] = run; cursor[i] = run; run += d;
  }
  if (t == 1023) off[N] = sums[1023];
}

__global__ void scatter_k(const int* __restrict__ src, const int* __restrict__ dst, int E,
                          int* __restrict__ cursor, int* __restrict__ csr){
  int i = blockIdx.x*blockDim.x + threadIdx.x;
  if (i < E){
    int p = atomicAdd(&cursor[dst[i]], 1);
    csr[p] = src[i];
  }
}

// ---------------- GEMM1: h1 = x @ W1 (128x128 tile, 8x8/thread), fused attention dots ----------------
__global__ __launch_bounds__(256) void gemm1_k(const float* __restrict__ x, const float* __restrict__ W,
    const float* __restrict__ attS, const float* __restrict__ attD,
    float* __restrict__ h1, float* __restrict__ aS, float* __restrict__ aD, int N){
  __shared__ float As[16][128];   // [k][m] 8KB
  __shared__ float Bs[16][128];   // [k][n] 8KB
  int tid = threadIdx.x;
  int tx = tid & 15, ty = tid >> 4;
  int m0 = blockIdx.x * 128;
  float acc[8][8];
  #pragma unroll
  for (int i=0;i<8;i++)
    #pragma unroll
    for (int j=0;j<8;j++) acc[i][j]=0.f;

  for (int k0 = 0; k0 < FIN; k0 += 16){
    #pragma unroll
    for (int l=0;l<2;l++){
      int fidx = tid + l*256;          // 0..511 over 128 rows x 4 float4-cols
      int r = fidx >> 2, cq = fidx & 3;
      int gr = m0 + r;
      float4 v = (gr < N) ? *(const float4*)&x[(size_t)gr*FIN + k0 + cq*4]
                          : make_float4(0.f,0.f,0.f,0.f);
      As[cq*4+0][r] = v.x; As[cq*4+1][r] = v.y; As[cq*4+2][r] = v.z; As[cq*4+3][r] = v.w;
    }
    #pragma unroll
    for (int l=0;l<2;l++){
      int fidx = tid + l*256;          // 0..511 over 16 rows x 32 float4-cols
      int r = fidx >> 5, c4 = fidx & 31;
      *(float4*)&Bs[r][c4*4] = *(const float4*)&W[(size_t)(k0+r)*D1 + c4*4];
    }
    __syncthreads();
    #pragma unroll
    for (int k=0;k<16;k++){
      float a[8], b[8];
      *(float4*)&a[0] = *(const float4*)&As[k][ty*8];
      *(float4*)&a[4] = *(const float4*)&As[k][ty*8+4];
      *(float4*)&b[0] = *(const float4*)&Bs[k][tx*8];
      *(float4*)&b[4] = *(const float4*)&Bs[k][tx*8+4];
      #pragma unroll
      for (int i=0;i<8;i++)
        #pragma unroll
        for (int j=0;j<8;j++) acc[i][j] += a[i]*b[j];
    }
    __syncthreads();
  }

  int h = tx >> 1;                 // head of this 8-col group
  int sub = (tx & 1) * 8;          // which half of the head's 16 channels
  #pragma unroll
  for (int i=0;i<8;i++){
    int r = m0 + ty*8 + i;
    if (r < N){
      *(float4*)&h1[(size_t)r*D1 + tx*8]     = make_float4(acc[i][0],acc[i][1],acc[i][2],acc[i][3]);
      *(float4*)&h1[(size_t)r*D1 + tx*8 + 4] = make_float4(acc[i][4],acc[i][5],acc[i][6],acc[i][7]);
      float pS=0.f, pD=0.f;
      #pragma unroll
      for (int j=0;j<8;j++){
        pS += acc[i][j]*attS[h*C1+sub+j];
        pD += acc[i][j]*attD[h*C1+sub+j];
      }
      pS += __shfl_xor(pS,1);
      pD += __shfl_xor(pD,1);
      if ((tx & 1) == 0){ aS[r*H1+h] = pS; aD[r*H1+h] = pD; }
    }
  }
}

// ---------------- node1: softmax aggregation (no max subtraction) + bias + elu ----------------
__global__ __launch_bounds__(256) void node1_k(const float* __restrict__ h1,
    const float* __restrict__ aS, const float* __restrict__ aD,
    const int* __restrict__ off, const int* __restrict__ csr,
    const float* __restrict__ b1, float* __restrict__ x2, int N){
  int n = blockIdx.x*4 + (threadIdx.x >> 6);
  if (n >= N) return;
  int lane = threadIdx.x & 63;
  int c = lane*2;                 // channels c, c+1 — both in head:
  int h = lane >> 3;              // head = c/16
  float ad = aD[n*H1+h];
  // self loop
  float e = lrelu(aS[n*H1+h] + ad);
  float p = __expf(e);
  float d = p;
  float2 hv = *(const float2*)&h1[(size_t)n*D1 + c];
  float acc0 = p*hv.x, acc1 = p*hv.y;
  int s0 = off[n], s1 = off[n+1];
  for (int i = s0; i < s1; ++i){
    int s = csr[i];
    float ee = lrelu(aS[s*H1+h] + ad);
    float pp = __expf(ee);
    float2 hh = *(const float2*)&h1[(size_t)s*D1 + c];
    d += pp; acc0 += pp*hh.x; acc1 += pp*hh.y;
  }
  float inv = 1.f / d;
  float o0 = acc0*inv + b1[c];
  float o1 = acc1*inv + b1[c+1];
  x2[(size_t)n*D1+c]   = elu(o0);
  x2[(size_t)n*D1+c+1] = elu(o1);
}

// ---------------- GEMM2: h2 = x2 @ W2, fused attention dots ----------------
__global__ __launch_bounds__(256) void gemm2_k(const float* __restrict__ x2, const float* __restrict__ W2,
    const float* __restrict__ attS2, const float* __restrict__ attD2,
    float* __restrict__ h2, float* __restrict__ aS2, float* __restrict__ aD2, int N){
  __shared__ float Ws[128*D2];     // 20 KB
  __shared__ float Xs[32][129];    // 16.5 KB, padded
  int tid = threadIdx.x;
  for (int i = tid; i < 128*D2; i += 256) Ws[i] = W2[i];
  int r0 = blockIdx.x*32;
  for (int i = tid; i < 32*128; i += 256){
    int r = i >> 7, c = i & 127;
    Xs[r][c] = (r0 + r < N) ? x2[(size_t)(r0+r)*D1 + c] : 0.f;
  }
  __syncthreads();
  int r = tid >> 3, g = tid & 7;   // r: 0..31 row, g: 0..7 col-group (5 cols each)
  float acc[5] = {0.f,0.f,0.f,0.f,0.f};
  for (int k = 0; k < 128; ++k){
    float xv = Xs[r][k];
    #pragma unroll
    for (int j=0;j<5;j++) acc[j] += xv * Ws[k*D2 + g*5 + j];
  }
  int row = r0 + r;
  float pS = 0.f, pD = 0.f;
  #pragma unroll
  for (int j=0;j<5;j++){ pS += acc[j]*attS2[g*5+j]; pD += acc[j]*attD2[g*5+j]; }
  #pragma unroll
  for (int o=4;o>0;o>>=1){ pS += __shfl_down(pS,o,8); pD += __shfl_down(pD,o,8); }
  if (row < N){
    #pragma unroll
    for (int j=0;j<5;j++) h2[(size_t)row*D2 + g*5 + j] = acc[j];
    if (g == 0){ aS2[row] = pS; aD2[row] = pD; }
  }
}

// ---------------- node2: softmax aggregation (no max) + bias -> out ----------------
__global__ __launch_bounds__(256) void node2_k(const float* __restrict__ h2,
    const float* __restrict__ aS2, const float* __restrict__ aD2,
    const int* __restrict__ off, const int* __restrict__ csr,
    const float* __restrict__ b2, float* __restrict__ out, int N){
  int n = blockIdx.x*4 + (threadIdx.x >> 6);
  if (n >= N) return;
  int lane = threadIdx.x & 63;
  float ad = aD2[n];
  float e = lrelu(aS2[n] + ad);
  float p = __expf(e);
  float d = p;
  float acc0 = 0.f, acc1 = 0.f;
  if (lane < 20){
    float2 v = *(const float2*)&h2[(size_t)n*D2 + lane*2];
    acc0 = p*v.x; acc1 = p*v.y;
  }
  int s0 = off[n], s1 = off[n+1];
  for (int i = s0; i < s1; ++i){
    int s = csr[i];
    float ee = lrelu(aS2[s] + ad);
    float pp = __expf(ee);
    d += pp;
    if (lane < 20){
      float2 v = *(const float2*)&h2[(size_t)s*D2 + lane*2];
      acc0 += pp*v.x; acc1 += pp*v.y;
    }
  }
  if (lane < 20){
    float inv = 1.f / d;
    out[(size_t)n*D2 + lane*2]     = acc0*inv + b2[lane*2];
    out[(size_t)n*D2 + lane*2 + 1] = acc1*inv + b2[lane*2+1];
  }
}

extern "C" void kernel_launch(void* const* d_in, const int* in_sizes, int n_in,
                              void* d_out, int out_size, void* d_ws, size_t ws_size,
                              hipStream_t stream){
  const float* x     = (const float*)d_in[0];
  const int*   ei    = (const int*)d_in[1];
  const float* W1    = (const float*)d_in[2];
  const float* attS1 = (const float*)d_in[3];
  const float* attD1 = (const float*)d_in[4];
  const float* b1    = (const float*)d_in[5];
  const float* W2    = (const float*)d_in[6];
  const float* attS2 = (const float*)d_in[7];
  const float* attD2 = (const float*)d_in[8];
  const float* b2    = (const float*)d_in[9];
  float* out = (float*)d_out;

  int N = in_sizes[0] / FIN;   // 50000
  int E = in_sizes[1] / 2;     // 1600000
  const int* src = ei;
  const int* dst = ei + E;

  char* ws = (char*)d_ws;
  size_t o = 0;
  auto alloc = [&](size_t bytes) -> void* {
    void* p = ws + o;
    o += (bytes + 255) & ~size_t(255);
    return p;
  };
  float* h1  = (float*)alloc((size_t)N*D1*sizeof(float));
  float* x2  = (float*)alloc((size_t)N*D1*sizeof(float));
  float* h2  = (float*)alloc((size_t)N*D2*sizeof(float));
  float* aS1 = (float*)alloc((size_t)N*H1*sizeof(float));
  float* aD1 = (float*)alloc((size_t)N*H1*sizeof(float));
  float* aS2 = (float*)alloc((size_t)N*sizeof(float));
  float* aD2 = (float*)alloc((size_t)N*sizeof(float));
  int*   off = (int*)alloc((size_t)(N+1)*sizeof(int));
  int*   cur = (int*)alloc((size_t)N*sizeof(int));
  int*   csr = (int*)alloc((size_t)E*sizeof(int));

  hipMemsetAsync(off, 0, (size_t)(N+1)*sizeof(int), stream);
  hist_k<<<(E+255)/256, 256, 0, stream>>>(dst, E, off);
  scan_k<<<1, 1024, 0, stream>>>(off, cur, N);
  scatter_k<<<(E+255)/256, 256, 0, stream>>>(src, dst, E, cur, csr);
  gemm1_k<<<(N+127)/128, 256, 0, stream>>>(x, W1, attS1, attD1, h1, aS1, aD1, N);
  node1_k<<<(N+3)/4, 256, 0, stream>>>(h1, aS1, aD1, off, csr, b1, x2, N);
  gemm2_k<<<(N+31)/32, 256, 0, stream>>>(x2, W2, attS2, attD2, h2, aS2, aD2, N);
  node2_k<<<(N+3)/4, 256, 0, stream>>>(h2, aS2, aD2, off, csr, b2, out, N);
}

// Round 3
// 597.669 us; speedup vs baseline: 1.3218x; 1.3218x over previous
//
#include <hip/hip_runtime.h>

#define FIN 256
#define H1 8
#define C1 16
#define D1 128   // H1*C1
#define D2 40

static __device__ __forceinline__ float lrelu(float x){ return fmaxf(x, 0.2f*x); }
static __device__ __forceinline__ float elu(float x){ return x > 0.f ? x : __expf(x) - 1.f; }

// ---------------- CSR build ----------------
__global__ void hist_k(const int* __restrict__ dst, int E, int* __restrict__ deg){
  int i = blockIdx.x*blockDim.x + threadIdx.x;
  if (i < E) atomicAdd(&deg[dst[i]], 1);
}

__global__ __launch_bounds__(1024) void scan_k(int* __restrict__ off, int* __restrict__ cursor, int N){
  __shared__ int sums[1024];
  int t = threadIdx.x;
  int CH = (N + 1023)/1024;
  int lo = t*CH; int hi = lo + CH;
  if (lo > N) lo = N;
  if (hi > N) hi = N;
  int s = 0;
  for (int i = lo; i < hi; ++i) s += off[i];
  sums[t] = s; __syncthreads();
  for (int o = 1; o < 1024; o <<= 1){
    int v = (t >= o) ? sums[t-o] : 0;
    __syncthreads();
    sums[t] += v;
    __syncthreads();
  }
  int run = (t == 0) ? 0 : sums[t-1];
  for (int i = lo; i < hi; ++i){
    int d = off[i];
    off[i] = run; cursor[i] = run; run += d;
  }
  if (t == 1023) off[N] = sums[1023];
}

__global__ void scatter_k(const int* __restrict__ src, const int* __restrict__ dst, int E,
                          int* __restrict__ cursor, int* __restrict__ csr, int* __restrict__ dstOf){
  int i = blockIdx.x*blockDim.x + threadIdx.x;
  if (i < E){
    int dd = dst[i];
    int p = atomicAdd(&cursor[dd], 1);
    csr[p] = src[i];
    dstOf[p] = dd;
  }
}

// ---------------- GEMM1: h1 = x @ W1 (128x128 tile, 8x8/thread), fused attention dots ----------------
__global__ __launch_bounds__(256) void gemm1_k(const float* __restrict__ x, const float* __restrict__ W,
    const float* __restrict__ attS, const float* __restrict__ attD,
    float* __restrict__ h1, float* __restrict__ aS, float* __restrict__ aD, int N){
  __shared__ float As[16][128];   // [k][m] 8KB
  __shared__ float Bs[16][128];   // [k][n] 8KB
  int tid = threadIdx.x;
  int tx = tid & 15, ty = tid >> 4;
  int m0 = blockIdx.x * 128;
  float acc[8][8];
  #pragma unroll
  for (int i=0;i<8;i++)
    #pragma unroll
    for (int j=0;j<8;j++) acc[i][j]=0.f;

  for (int k0 = 0; k0 < FIN; k0 += 16){
    #pragma unroll
    for (int l=0;l<2;l++){
      int fidx = tid + l*256;          // 0..511 over 128 rows x 4 float4-cols
      int r = fidx >> 2, cq = fidx & 3;
      int gr = m0 + r;
      float4 v = (gr < N) ? *(const float4*)&x[(size_t)gr*FIN + k0 + cq*4]
                          : make_float4(0.f,0.f,0.f,0.f);
      As[cq*4+0][r] = v.x; As[cq*4+1][r] = v.y; As[cq*4+2][r] = v.z; As[cq*4+3][r] = v.w;
    }
    #pragma unroll
    for (int l=0;l<2;l++){
      int fidx = tid + l*256;          // 0..511 over 16 rows x 32 float4-cols
      int r = fidx >> 5, c4 = fidx & 31;
      *(float4*)&Bs[r][c4*4] = *(const float4*)&W[(size_t)(k0+r)*D1 + c4*4];
    }
    __syncthreads();
    #pragma unroll
    for (int k=0;k<16;k++){
      float a[8], b[8];
      *(float4*)&a[0] = *(const float4*)&As[k][ty*8];
      *(float4*)&a[4] = *(const float4*)&As[k][ty*8+4];
      *(float4*)&b[0] = *(const float4*)&Bs[k][tx*8];
      *(float4*)&b[4] = *(const float4*)&Bs[k][tx*8+4];
      #pragma unroll
      for (int i=0;i<8;i++)
        #pragma unroll
        for (int j=0;j<8;j++) acc[i][j] += a[i]*b[j];
    }
    __syncthreads();
  }

  int h = tx >> 1;                 // head of this 8-col group
  int sub = (tx & 1) * 8;          // which half of the head's 16 channels
  #pragma unroll
  for (int i=0;i<8;i++){
    int r = m0 + ty*8 + i;
    if (r < N){
      *(float4*)&h1[(size_t)r*D1 + tx*8]     = make_float4(acc[i][0],acc[i][1],acc[i][2],acc[i][3]);
      *(float4*)&h1[(size_t)r*D1 + tx*8 + 4] = make_float4(acc[i][4],acc[i][5],acc[i][6],acc[i][7]);
      float pS=0.f, pD=0.f;
      #pragma unroll
      for (int j=0;j<8;j++){
        pS += acc[i][j]*attS[h*C1+sub+j];
        pD += acc[i][j]*attD[h*C1+sub+j];
      }
      pS += __shfl_xor(pS,1);
      pD += __shfl_xor(pD,1);
      if ((tx & 1) == 0){ aS[r*H1+h] = pS; aD[r*H1+h] = pD; }
    }
  }
}

// ---------------- node1: softmax aggregation, 4-deep gather pipeline ----------------
__global__ __launch_bounds__(64) void node1_k(const float* __restrict__ h1,
    const float* __restrict__ aS, const float* __restrict__ aD,
    const int* __restrict__ off, const int* __restrict__ csr,
    const float* __restrict__ b1, float* __restrict__ x2, int N){
  int n = blockIdx.x;
  int lane = threadIdx.x;
  int c = lane*2;                 // channels c, c+1
  int h = lane >> 3;              // head = c/16
  float ad = aD[n*H1+h];
  float p = __expf(lrelu(aS[n*H1+h] + ad));   // self loop
  float d = p;
  float2 hv = *(const float2*)&h1[(size_t)n*D1 + c];
  float acc0 = p*hv.x, acc1 = p*hv.y;
  int i = off[n], e = off[n+1];
  for (; i+4 <= e; i += 4){
    int s0=csr[i], s1=csr[i+1], s2=csr[i+2], s3=csr[i+3];
    float a0 = aS[s0*H1+h], a1 = aS[s1*H1+h], a2 = aS[s2*H1+h], a3 = aS[s3*H1+h];
    float2 v0 = *(const float2*)&h1[(size_t)s0*D1+c];
    float2 v1 = *(const float2*)&h1[(size_t)s1*D1+c];
    float2 v2 = *(const float2*)&h1[(size_t)s2*D1+c];
    float2 v3 = *(const float2*)&h1[(size_t)s3*D1+c];
    float p0 = __expf(lrelu(a0+ad));
    float p1 = __expf(lrelu(a1+ad));
    float p2_ = __expf(lrelu(a2+ad));
    float p3 = __expf(lrelu(a3+ad));
    d += p0+p1+p2_+p3;
    acc0 += p0*v0.x + p1*v1.x + p2_*v2.x + p3*v3.x;
    acc1 += p0*v0.y + p1*v1.y + p2_*v2.y + p3*v3.y;
  }
  for (; i < e; ++i){
    int s = csr[i];
    float pp = __expf(lrelu(aS[s*H1+h] + ad));
    float2 vv = *(const float2*)&h1[(size_t)s*D1+c];
    d += pp; acc0 += pp*vv.x; acc1 += pp*vv.y;
  }
  float inv = 1.f/d;
  float o0 = acc0*inv + b1[c];
  float o1 = acc1*inv + b1[c+1];
  x2[(size_t)n*D1+c]   = elu(o0);
  x2[(size_t)n*D1+c+1] = elu(o1);
}

// ---------------- GEMM2: h2 = x2 @ W2, fused attention dots ----------------
__global__ __launch_bounds__(256) void gemm2_k(const float* __restrict__ x2, const float* __restrict__ W2,
    const float* __restrict__ attS2, const float* __restrict__ attD2,
    float* __restrict__ h2, float* __restrict__ aS2, float* __restrict__ aD2, int N){
  __shared__ float Ws[128*D2];     // 20 KB
  __shared__ float Xs[32][129];    // 16.5 KB, padded
  int tid = threadIdx.x;
  for (int i = tid; i < 128*D2; i += 256) Ws[i] = W2[i];
  int r0 = blockIdx.x*32;
  for (int i = tid; i < 32*128; i += 256){
    int r = i >> 7, c = i & 127;
    Xs[r][c] = (r0 + r < N) ? x2[(size_t)(r0+r)*D1 + c] : 0.f;
  }
  __syncthreads();
  int r = tid >> 3, g = tid & 7;   // r: 0..31 row, g: 0..7 col-group (5 cols each)
  float acc[5] = {0.f,0.f,0.f,0.f,0.f};
  for (int k = 0; k < 128; ++k){
    float xv = Xs[r][k];
    #pragma unroll
    for (int j=0;j<5;j++) acc[j] += xv * Ws[k*D2 + g*5 + j];
  }
  int row = r0 + r;
  float pS = 0.f, pD = 0.f;
  #pragma unroll
  for (int j=0;j<5;j++){ pS += acc[j]*attS2[g*5+j]; pD += acc[j]*attD2[g*5+j]; }
  #pragma unroll
  for (int o=4;o>0;o>>=1){ pS += __shfl_down(pS,o,8); pD += __shfl_down(pD,o,8); }
  if (row < N){
    #pragma unroll
    for (int j=0;j<5;j++) h2[(size_t)row*D2 + g*5 + j] = acc[j];
    if (g == 0){ aS2[row] = pS; aD2[row] = pD; }
  }
}

// ---------------- edge2: precompute exp(lrelu(aS2[src]+aD2[dst])) in CSR order ----------------
__global__ void edge2_k(const int* __restrict__ csr, const int* __restrict__ dstOf, int E,
                        const float* __restrict__ aS2, const float* __restrict__ aD2,
                        float* __restrict__ p2){
  int i = blockIdx.x*blockDim.x + threadIdx.x;
  if (i < E) p2[i] = __expf(lrelu(aS2[csr[i]] + aD2[dstOf[i]]));
}

// ---------------- node2: softmax aggregation, 8-deep gather pipeline ----------------
__global__ __launch_bounds__(64) void node2_k(const float* __restrict__ h2,
    const float* __restrict__ p2,
    const float* __restrict__ aS2, const float* __restrict__ aD2,
    const int* __restrict__ off, const int* __restrict__ csr,
    const float* __restrict__ b2, float* __restrict__ out, int N){
  int n = blockIdx.x;
  int lane = threadIdx.x;
  bool act = lane < 20;
  int c = lane*2;
  float ps = __expf(lrelu(aS2[n] + aD2[n]));   // self loop
  float d = ps;
  float acc0 = 0.f, acc1 = 0.f;
  if (act){ float2 v = *(const float2*)&h2[(size_t)n*D2 + c]; acc0 = ps*v.x; acc1 = ps*v.y; }
  int i = off[n], e = off[n+1];
  for (; i+8 <= e; i += 8){
    int s[8]; float p[8]; float2 v[8];
    #pragma unroll
    for (int u=0;u<8;u++){ s[u] = csr[i+u]; p[u] = p2[i+u]; }
    if (act){
      #pragma unroll
      for (int u=0;u<8;u++) v[u] = *(const float2*)&h2[(size_t)s[u]*D2 + c];
    } else {
      #pragma unroll
      for (int u=0;u<8;u++) v[u] = make_float2(0.f,0.f);
    }
    #pragma unroll
    for (int u=0;u<8;u++){ d += p[u]; acc0 += p[u]*v[u].x; acc1 += p[u]*v[u].y; }
  }
  for (; i < e; ++i){
    float pp = p2[i];
    d += pp;
    if (act){
      float2 vv = *(const float2*)&h2[(size_t)csr[i]*D2 + c];
      acc0 += pp*vv.x; acc1 += pp*vv.y;
    }
  }
  if (act){
    float inv = 1.f/d;
    out[(size_t)n*D2 + c]     = acc0*inv + b2[c];
    out[(size_t)n*D2 + c + 1] = acc1*inv + b2[c+1];
  }
}

extern "C" void kernel_launch(void* const* d_in, const int* in_sizes, int n_in,
                              void* d_out, int out_size, void* d_ws, size_t ws_size,
                              hipStream_t stream){
  const float* x     = (const float*)d_in[0];
  const int*   ei    = (const int*)d_in[1];
  const float* W1    = (const float*)d_in[2];
  const float* attS1 = (const float*)d_in[3];
  const float* attD1 = (const float*)d_in[4];
  const float* b1    = (const float*)d_in[5];
  const float* W2    = (const float*)d_in[6];
  const float* attS2 = (const float*)d_in[7];
  const float* attD2 = (const float*)d_in[8];
  const float* b2    = (const float*)d_in[9];
  float* out = (float*)d_out;

  int N = in_sizes[0] / FIN;   // 50000
  int E = in_sizes[1] / 2;     // 1600000
  const int* src = ei;
  const int* dst = ei + E;

  char* ws = (char*)d_ws;
  size_t o = 0;
  auto alloc = [&](size_t bytes) -> void* {
    void* p = ws + o;
    o += (bytes + 255) & ~size_t(255);
    return p;
  };
  float* h1    = (float*)alloc((size_t)N*D1*sizeof(float));
  float* x2    = (float*)alloc((size_t)N*D1*sizeof(float));
  float* h2    = (float*)alloc((size_t)N*D2*sizeof(float));
  float* aS1   = (float*)alloc((size_t)N*H1*sizeof(float));
  float* aD1   = (float*)alloc((size_t)N*H1*sizeof(float));
  float* aS2   = (float*)alloc((size_t)N*sizeof(float));
  float* aD2   = (float*)alloc((size_t)N*sizeof(float));
  int*   off   = (int*)alloc((size_t)(N+1)*sizeof(int));
  int*   cur   = (int*)alloc((size_t)N*sizeof(int));
  int*   csr   = (int*)alloc((size_t)E*sizeof(int));
  int*   dstOf = (int*)alloc((size_t)E*sizeof(int));
  float* p2    = (float*)alloc((size_t)E*sizeof(float));

  hipMemsetAsync(off, 0, (size_t)(N+1)*sizeof(int), stream);
  hist_k<<<(E+255)/256, 256, 0, stream>>>(dst, E, off);
  scan_k<<<1, 1024, 0, stream>>>(off, cur, N);
  scatter_k<<<(E+255)/256, 256, 0, stream>>>(src, dst, E, cur, csr, dstOf);
  gemm1_k<<<(N+127)/128, 256, 0, stream>>>(x, W1, attS1, attD1, h1, aS1, aD1, N);
  node1_k<<<N, 64, 0, stream>>>(h1, aS1, aD1, off, csr, b1, x2, N);
  gemm2_k<<<(N+31)/32, 256, 0, stream>>>(x2, W2, attS2, attD2, h2, aS2, aD2, N);
  edge2_k<<<(E+255)/256, 256, 0, stream>>>(csr, dstOf, E, aS2, aD2, p2);
  node2_k<<<N, 64, 0, stream>>>(h2, p2, aS2, aD2, off, csr, b2, out, N);
}

// Round 4
// 533.722 us; speedup vs baseline: 1.4802x; 1.1198x over previous
//
#include <hip/hip_runtime.h>

#define FIN 256
#define H1 8
#define C1 16
#define D1 128   // H1*C1
#define D2 40

static __device__ __forceinline__ float lrelu(float x){ return fmaxf(x, 0.2f*x); }
static __device__ __forceinline__ float elu(float x){ return x > 0.f ? x : __expf(x) - 1.f; }
static __device__ __forceinline__ unsigned short f2bf(float f){      // RNE bf16
  unsigned u = __float_as_uint(f);
  return (unsigned short)((u + 0x7fffu + ((u >> 16) & 1u)) >> 16);
}
static __device__ __forceinline__ float bf_lo(unsigned v){ return __uint_as_float(v << 16); }
static __device__ __forceinline__ float bf_hi(unsigned v){ return __uint_as_float(v & 0xffff0000u); }

// ---------------- CSR build ----------------
__global__ void hist_k(const int* __restrict__ dst, int E, int* __restrict__ deg){
  int i = blockIdx.x*blockDim.x + threadIdx.x;
  if (i < E) atomicAdd(&deg[dst[i]], 1);
}

__global__ __launch_bounds__(1024) void scan_k(int* __restrict__ off, int* __restrict__ cursor, int N){
  __shared__ int sums[1024];
  int t = threadIdx.x;
  int CH = (N + 1023)/1024;
  int lo = t*CH; int hi = lo + CH;
  if (lo > N) lo = N;
  if (hi > N) hi = N;
  int s = 0;
  for (int i = lo; i < hi; ++i) s += off[i];
  sums[t] = s; __syncthreads();
  for (int o = 1; o < 1024; o <<= 1){
    int v = (t >= o) ? sums[t-o] : 0;
    __syncthreads();
    sums[t] += v;
    __syncthreads();
  }
  int run = (t == 0) ? 0 : sums[t-1];
  for (int i = lo; i < hi; ++i){
    int d = off[i];
    off[i] = run; cursor[i] = run; run += d;
  }
  if (t == 1023) off[N] = sums[1023];
}

__global__ void scatter_k(const int* __restrict__ src, const int* __restrict__ dst, int E,
                          int* __restrict__ cursor, int* __restrict__ csr){
  int i = blockIdx.x*blockDim.x + threadIdx.x;
  if (i < E){
    int p = atomicAdd(&cursor[dst[i]], 1);
    csr[p] = src[i];
  }
}

// ---------------- GEMM1: h1(bf16) = x @ W1 (128x128 tile, 8x8/thread), fused attention dots ----------------
__global__ __launch_bounds__(256) void gemm1_k(const float* __restrict__ x, const float* __restrict__ W,
    const float* __restrict__ attS, const float* __restrict__ attD,
    unsigned short* __restrict__ h1b, float* __restrict__ aS, float* __restrict__ aD, int N){
  __shared__ float As[16][128];   // [k][m] 8KB
  __shared__ float Bs[16][128];   // [k][n] 8KB
  int tid = threadIdx.x;
  int tx = tid & 15, ty = tid >> 4;
  int m0 = blockIdx.x * 128;
  float acc[8][8];
  #pragma unroll
  for (int i=0;i<8;i++)
    #pragma unroll
    for (int j=0;j<8;j++) acc[i][j]=0.f;

  for (int k0 = 0; k0 < FIN; k0 += 16){
    #pragma unroll
    for (int l=0;l<2;l++){
      int fidx = tid + l*256;          // 0..511 over 128 rows x 4 float4-cols
      int r = fidx >> 2, cq = fidx & 3;
      int gr = m0 + r;
      float4 v = (gr < N) ? *(const float4*)&x[(size_t)gr*FIN + k0 + cq*4]
                          : make_float4(0.f,0.f,0.f,0.f);
      As[cq*4+0][r] = v.x; As[cq*4+1][r] = v.y; As[cq*4+2][r] = v.z; As[cq*4+3][r] = v.w;
    }
    #pragma unroll
    for (int l=0;l<2;l++){
      int fidx = tid + l*256;          // 0..511 over 16 rows x 32 float4-cols
      int r = fidx >> 5, c4 = fidx & 31;
      *(float4*)&Bs[r][c4*4] = *(const float4*)&W[(size_t)(k0+r)*D1 + c4*4];
    }
    __syncthreads();
    #pragma unroll
    for (int k=0;k<16;k++){
      float a[8], b[8];
      *(float4*)&a[0] = *(const float4*)&As[k][ty*8];
      *(float4*)&a[4] = *(const float4*)&As[k][ty*8+4];
      *(float4*)&b[0] = *(const float4*)&Bs[k][tx*8];
      *(float4*)&b[4] = *(const float4*)&Bs[k][tx*8+4];
      #pragma unroll
      for (int i=0;i<8;i++)
        #pragma unroll
        for (int j=0;j<8;j++) acc[i][j] += a[i]*b[j];
    }
    __syncthreads();
  }

  int h = tx >> 1;                 // head of this 8-col group
  int sub = (tx & 1) * 8;          // which half of the head's 16 channels
  #pragma unroll
  for (int i=0;i<8;i++){
    int r = m0 + ty*8 + i;
    if (r < N){
      unsigned pk0 = (unsigned)f2bf(acc[i][0]) | ((unsigned)f2bf(acc[i][1]) << 16);
      unsigned pk1 = (unsigned)f2bf(acc[i][2]) | ((unsigned)f2bf(acc[i][3]) << 16);
      unsigned pk2 = (unsigned)f2bf(acc[i][4]) | ((unsigned)f2bf(acc[i][5]) << 16);
      unsigned pk3 = (unsigned)f2bf(acc[i][6]) | ((unsigned)f2bf(acc[i][7]) << 16);
      *(uint4*)&h1b[(size_t)r*D1 + tx*8] = make_uint4(pk0,pk1,pk2,pk3);
      float pS=0.f, pD=0.f;
      #pragma unroll
      for (int j=0;j<8;j++){
        pS += acc[i][j]*attS[h*C1+sub+j];
        pD += acc[i][j]*attD[h*C1+sub+j];
      }
      pS += __shfl_xor(pS,1);
      pD += __shfl_xor(pD,1);
      if ((tx & 1) == 0){ aS[r*H1+h] = pS; aD[r*H1+h] = pD; }
    }
  }
}

// ---------------- node1: softmax aggregation over bf16 h1, 8-deep gather pipeline ----------------
__global__ __launch_bounds__(64) void node1_k(const unsigned short* __restrict__ h1b,
    const float* __restrict__ aS, const float* __restrict__ aD,
    const int* __restrict__ off, const int* __restrict__ csr,
    const float* __restrict__ b1, float* __restrict__ x2, int N){
  int n = blockIdx.x;
  int lane = threadIdx.x;
  int c = lane*2;                 // channels c, c+1
  int h = lane >> 3;              // head = c/16
  float ad = aD[n*H1+h];
  float p = __expf(lrelu(aS[n*H1+h] + ad));   // self loop
  float d = p;
  unsigned hv = *(const unsigned*)&h1b[(size_t)n*D1 + c];
  float acc0 = p*bf_lo(hv), acc1 = p*bf_hi(hv);
  int i = off[n], e = off[n+1];
  for (; i+8 <= e; i += 8){
    int s[8]; float a[8]; unsigned v[8];
    #pragma unroll
    for (int u=0;u<8;u++) s[u] = csr[i+u];
    #pragma unroll
    for (int u=0;u<8;u++) a[u] = aS[s[u]*H1+h];
    #pragma unroll
    for (int u=0;u<8;u++) v[u] = *(const unsigned*)&h1b[(size_t)s[u]*D1 + c];
    #pragma unroll
    for (int u=0;u<8;u++){
      float pp = __expf(lrelu(a[u]+ad));
      d += pp; acc0 += pp*bf_lo(v[u]); acc1 += pp*bf_hi(v[u]);
    }
  }
  for (; i < e; ++i){
    int s = csr[i];
    float pp = __expf(lrelu(aS[s*H1+h] + ad));
    unsigned vv = *(const unsigned*)&h1b[(size_t)s*D1 + c];
    d += pp; acc0 += pp*bf_lo(vv); acc1 += pp*bf_hi(vv);
  }
  float inv = 1.f/d;
  float o0 = acc0*inv + b1[c];
  float o1 = acc1*inv + b1[c+1];
  x2[(size_t)n*D1+c]   = elu(o0);
  x2[(size_t)n*D1+c+1] = elu(o1);
}

// ---------------- GEMM2: h2 = x2 @ W2, fused attention dots ----------------
__global__ __launch_bounds__(256) void gemm2_k(const float* __restrict__ x2, const float* __restrict__ W2,
    const float* __restrict__ attS2, const float* __restrict__ attD2,
    float* __restrict__ h2, float* __restrict__ aS2, float* __restrict__ aD2, int N){
  __shared__ float Ws[128*D2];     // 20 KB
  __shared__ float Xs[32][129];    // 16.5 KB, padded
  int tid = threadIdx.x;
  for (int i = tid; i < 128*D2; i += 256) Ws[i] = W2[i];
  int r0 = blockIdx.x*32;
  for (int i = tid; i < 32*128; i += 256){
    int r = i >> 7, c = i & 127;
    Xs[r][c] = (r0 + r < N) ? x2[(size_t)(r0+r)*D1 + c] : 0.f;
  }
  __syncthreads();
  int r = tid >> 3, g = tid & 7;   // r: 0..31 row, g: 0..7 col-group (5 cols each)
  float acc[5] = {0.f,0.f,0.f,0.f,0.f};
  for (int k = 0; k < 128; ++k){
    float xv = Xs[r][k];
    #pragma unroll
    for (int j=0;j<5;j++) acc[j] += xv * Ws[k*D2 + g*5 + j];
  }
  int row = r0 + r;
  float pS = 0.f, pD = 0.f;
  #pragma unroll
  for (int j=0;j<5;j++){ pS += acc[j]*attS2[g*5+j]; pD += acc[j]*attD2[g*5+j]; }
  #pragma unroll
  for (int o=4;o>0;o>>=1){ pS += __shfl_down(pS,o,8); pD += __shfl_down(pD,o,8); }
  if (row < N){
    #pragma unroll
    for (int j=0;j<5;j++) h2[(size_t)row*D2 + g*5 + j] = acc[j];
    if (g == 0){ aS2[row] = pS; aD2[row] = pD; }
  }
}

// ---------------- edge2: p2[i] = exp(lrelu(aS2[csr[i]] + aD2[n])), node-parallel (dst implicit) ----------------
__global__ __launch_bounds__(64) void edge2_k(const float* __restrict__ aS2, const float* __restrict__ aD2,
                        const int* __restrict__ off, const int* __restrict__ csr,
                        float* __restrict__ p2, int N){
  int n = blockIdx.x;
  float ad = aD2[n];
  int s0 = off[n], s1 = off[n+1];
  for (int i = s0 + threadIdx.x; i < s1; i += 64)
    p2[i] = __expf(lrelu(aS2[csr[i]] + ad));
}

// ---------------- node2: softmax aggregation, 8-deep gather pipeline ----------------
__global__ __launch_bounds__(64) void node2_k(const float* __restrict__ h2,
    const float* __restrict__ p2,
    const float* __restrict__ aS2, const float* __restrict__ aD2,
    const int* __restrict__ off, const int* __restrict__ csr,
    const float* __restrict__ b2, float* __restrict__ out, int N){
  int n = blockIdx.x;
  int lane = threadIdx.x;
  bool act = lane < 20;
  int c = lane*2;
  float ps = __expf(lrelu(aS2[n] + aD2[n]));   // self loop
  float d = ps;
  float acc0 = 0.f, acc1 = 0.f;
  if (act){ float2 v = *(const float2*)&h2[(size_t)n*D2 + c]; acc0 = ps*v.x; acc1 = ps*v.y; }
  int i = off[n], e = off[n+1];
  for (; i+8 <= e; i += 8){
    int s[8]; float p[8]; float2 v[8];
    #pragma unroll
    for (int u=0;u<8;u++){ s[u] = csr[i+u]; p[u] = p2[i+u]; }
    if (act){
      #pragma unroll
      for (int u=0;u<8;u++) v[u] = *(const float2*)&h2[(size_t)s[u]*D2 + c];
    } else {
      #pragma unroll
      for (int u=0;u<8;u++) v[u] = make_float2(0.f,0.f);
    }
    #pragma unroll
    for (int u=0;u<8;u++){ d += p[u]; acc0 += p[u]*v[u].x; acc1 += p[u]*v[u].y; }
  }
  for (; i < e; ++i){
    float pp = p2[i];
    d += pp;
    if (act){
      float2 vv = *(const float2*)&h2[(size_t)csr[i]*D2 + c];
      acc0 += pp*vv.x; acc1 += pp*vv.y;
    }
  }
  if (act){
    float inv = 1.f/d;
    out[(size_t)n*D2 + c]     = acc0*inv + b2[c];
    out[(size_t)n*D2 + c + 1] = acc1*inv + b2[c+1];
  }
}

extern "C" void kernel_launch(void* const* d_in, const int* in_sizes, int n_in,
                              void* d_out, int out_size, void* d_ws, size_t ws_size,
                              hipStream_t stream){
  const float* x     = (const float*)d_in[0];
  const int*   ei    = (const int*)d_in[1];
  const float* W1    = (const float*)d_in[2];
  const float* attS1 = (const float*)d_in[3];
  const float* attD1 = (const float*)d_in[4];
  const float* b1    = (const float*)d_in[5];
  const float* W2    = (const float*)d_in[6];
  const float* attS2 = (const float*)d_in[7];
  const float* attD2 = (const float*)d_in[8];
  const float* b2    = (const float*)d_in[9];
  float* out = (float*)d_out;

  int N = in_sizes[0] / FIN;   // 50000
  int E = in_sizes[1] / 2;     // 1600000
  const int* src = ei;
  const int* dst = ei + E;

  char* ws = (char*)d_ws;
  size_t o = 0;
  auto alloc = [&](size_t bytes) -> void* {
    void* p = ws + o;
    o += (bytes + 255) & ~size_t(255);
    return p;
  };
  unsigned short* h1b = (unsigned short*)alloc((size_t)N*D1*sizeof(unsigned short));
  float* x2    = (float*)alloc((size_t)N*D1*sizeof(float));
  float* h2    = (float*)alloc((size_t)N*D2*sizeof(float));
  float* aS1   = (float*)alloc((size_t)N*H1*sizeof(float));
  float* aD1   = (float*)alloc((size_t)N*H1*sizeof(float));
  float* aS2   = (float*)alloc((size_t)N*sizeof(float));
  float* aD2   = (float*)alloc((size_t)N*sizeof(float));
  int*   off   = (int*)alloc((size_t)(N+1)*sizeof(int));
  int*   cur   = (int*)alloc((size_t)N*sizeof(int));
  int*   csr   = (int*)alloc((size_t)E*sizeof(int));
  float* p2    = (float*)alloc((size_t)E*sizeof(float));

  hipMemsetAsync(off, 0, (size_t)(N+1)*sizeof(int), stream);
  hist_k<<<(E+255)/256, 256, 0, stream>>>(dst, E, off);
  scan_k<<<1, 1024, 0, stream>>>(off, cur, N);
  scatter_k<<<(E+255)/256, 256, 0, stream>>>(src, dst, E, cur, csr);
  gemm1_k<<<(N+127)/128, 256, 0, stream>>>(x, W1, attS1, attD1, h1b, aS1, aD1, N);
  node1_k<<<N, 64, 0, stream>>>(h1b, aS1, aD1, off, csr, b1, x2, N);
  gemm2_k<<<(N+31)/32, 256, 0, stream>>>(x2, W2, attS2, attD2, h2, aS2, aD2, N);
  edge2_k<<<N, 64, 0, stream>>>(aS2, aD2, off, csr, p2, N);
  node2_k<<<N, 64, 0, stream>>>(h2, p2, aS2, aD2, off, csr, b2, out, N);
}

// Round 5
// 511.314 us; speedup vs baseline: 1.5450x; 1.0438x over previous
//
#include <hip/hip_runtime.h>

#define FIN 256
#define H1 8
#define C1 16
#define D1 128   // H1*C1
#define D2 40
#define NPASS 16

static __device__ __forceinline__ float lrelu(float x){ return fmaxf(x, 0.2f*x); }
static __device__ __forceinline__ float elu(float x){ return x > 0.f ? x : __expf(x) - 1.f; }
static __device__ __forceinline__ unsigned short f2bf(float f){      // RNE bf16
  unsigned u = __float_as_uint(f);
  return (unsigned short)((u + 0x7fffu + ((u >> 16) & 1u)) >> 16);
}
static __device__ __forceinline__ float bf_lo(unsigned v){ return __uint_as_float(v << 16); }
static __device__ __forceinline__ float bf_hi(unsigned v){ return __uint_as_float(v & 0xffff0000u); }

// ---------------- CSR build ----------------
__global__ void hist_k(const int* __restrict__ dst, int E, int* __restrict__ deg){
  int i = blockIdx.x*blockDim.x + threadIdx.x;
  if (i < E) atomicAdd(&deg[dst[i]], 1);
}

__global__ __launch_bounds__(1024) void scan_k(int* __restrict__ off, int* __restrict__ cursor, int N){
  __shared__ int sums[1024];
  int t = threadIdx.x;
  int CH = (N + 1023)/1024;
  int lo = t*CH; int hi = lo + CH;
  if (lo > N) lo = N;
  if (hi > N) hi = N;
  int s = 0;
  for (int i = lo; i < hi; ++i) s += off[i];
  sums[t] = s; __syncthreads();
  for (int o = 1; o < 1024; o <<= 1){
    int v = (t >= o) ? sums[t-o] : 0;
    __syncthreads();
    sums[t] += v;
    __syncthreads();
  }
  int run = (t == 0) ? 0 : sums[t-1];
  for (int i = lo; i < hi; ++i){
    int d = off[i];
    off[i] = run; cursor[i] = run; run += d;
  }
  if (t == 1023) off[N] = sums[1023];
}

// multi-pass scatter: pass p handles dst in [N*p/NPASS, N*(p+1)/NPASS) so csr writes
// land in a ~400KB window and cursor atomics hit a ~12.5KB hot slice.
__global__ __launch_bounds__(256) void scatter_mp(const int* __restrict__ src, const int* __restrict__ dst,
                          int E, int* __restrict__ cursor, int* __restrict__ csr, int N){
  int stride = gridDim.x*blockDim.x;
  int tid0 = blockIdx.x*blockDim.x + threadIdx.x;
  for (int p = 0; p < NPASS; ++p){
    int lo = (int)(((long long)N*p)/NPASS);
    int hi = (int)(((long long)N*(p+1))/NPASS);
    for (int i = tid0; i < E; i += stride){
      int dd = dst[i];
      if (dd >= lo && dd < hi){
        int pos = atomicAdd(&cursor[dd], 1);
        csr[pos] = src[i];
      }
    }
  }
}

// ---------------- GEMM1: h1(bf16) = x @ W1 (128x128 tile, 8x8/thread), fused attention dots ----------------
__global__ __launch_bounds__(256) void gemm1_k(const float* __restrict__ x, const float* __restrict__ W,
    const float* __restrict__ attS, const float* __restrict__ attD,
    unsigned short* __restrict__ h1b, float* __restrict__ aS, float* __restrict__ aD, int N){
  __shared__ float As[16][128];   // [k][m] 8KB
  __shared__ float Bs[16][128];   // [k][n] 8KB
  int tid = threadIdx.x;
  int tx = tid & 15, ty = tid >> 4;
  int m0 = blockIdx.x * 128;
  float acc[8][8];
  #pragma unroll
  for (int i=0;i<8;i++)
    #pragma unroll
    for (int j=0;j<8;j++) acc[i][j]=0.f;

  for (int k0 = 0; k0 < FIN; k0 += 16){
    #pragma unroll
    for (int l=0;l<2;l++){
      int fidx = tid + l*256;          // 0..511 over 128 rows x 4 float4-cols
      int r = fidx >> 2, cq = fidx & 3;
      int gr = m0 + r;
      float4 v = (gr < N) ? *(const float4*)&x[(size_t)gr*FIN + k0 + cq*4]
                          : make_float4(0.f,0.f,0.f,0.f);
      As[cq*4+0][r] = v.x; As[cq*4+1][r] = v.y; As[cq*4+2][r] = v.z; As[cq*4+3][r] = v.w;
    }
    #pragma unroll
    for (int l=0;l<2;l++){
      int fidx = tid + l*256;          // 0..511 over 16 rows x 32 float4-cols
      int r = fidx >> 5, c4 = fidx & 31;
      *(float4*)&Bs[r][c4*4] = *(const float4*)&W[(size_t)(k0+r)*D1 + c4*4];
    }
    __syncthreads();
    #pragma unroll
    for (int k=0;k<16;k++){
      float a[8], b[8];
      *(float4*)&a[0] = *(const float4*)&As[k][ty*8];
      *(float4*)&a[4] = *(const float4*)&As[k][ty*8+4];
      *(float4*)&b[0] = *(const float4*)&Bs[k][tx*8];
      *(float4*)&b[4] = *(const float4*)&Bs[k][tx*8+4];
      #pragma unroll
      for (int i=0;i<8;i++)
        #pragma unroll
        for (int j=0;j<8;j++) acc[i][j] += a[i]*b[j];
    }
    __syncthreads();
  }

  int h = tx >> 1;                 // head of this 8-col group
  int sub = (tx & 1) * 8;          // which half of the head's 16 channels
  #pragma unroll
  for (int i=0;i<8;i++){
    int r = m0 + ty*8 + i;
    if (r < N){
      unsigned pk0 = (unsigned)f2bf(acc[i][0]) | ((unsigned)f2bf(acc[i][1]) << 16);
      unsigned pk1 = (unsigned)f2bf(acc[i][2]) | ((unsigned)f2bf(acc[i][3]) << 16);
      unsigned pk2 = (unsigned)f2bf(acc[i][4]) | ((unsigned)f2bf(acc[i][5]) << 16);
      unsigned pk3 = (unsigned)f2bf(acc[i][6]) | ((unsigned)f2bf(acc[i][7]) << 16);
      *(uint4*)&h1b[(size_t)r*D1 + tx*8] = make_uint4(pk0,pk1,pk2,pk3);
      float pS=0.f, pD=0.f;
      #pragma unroll
      for (int j=0;j<8;j++){
        pS += acc[i][j]*attS[h*C1+sub+j];
        pD += acc[i][j]*attD[h*C1+sub+j];
      }
      pS += __shfl_xor(pS,1);
      pD += __shfl_xor(pD,1);
      if ((tx & 1) == 0){ aS[r*H1+h] = pS; aD[r*H1+h] = pD; }
    }
  }
}

// ---------------- node1: softmax aggregation over bf16 h1, 8-deep gather pipeline ----------------
__global__ __launch_bounds__(64) void node1_k(const unsigned short* __restrict__ h1b,
    const float* __restrict__ aS, const float* __restrict__ aD,
    const int* __restrict__ off, const int* __restrict__ csr,
    const float* __restrict__ b1, float* __restrict__ x2, int N){
  int n = blockIdx.x;
  int lane = threadIdx.x;
  int c = lane*2;                 // channels c, c+1
  int h = lane >> 3;              // head = c/16
  float ad = aD[n*H1+h];
  float p = __expf(lrelu(aS[n*H1+h] + ad));   // self loop
  float d = p;
  unsigned hv = *(const unsigned*)&h1b[(size_t)n*D1 + c];
  float acc0 = p*bf_lo(hv), acc1 = p*bf_hi(hv);
  int i = off[n], e = off[n+1];
  for (; i+8 <= e; i += 8){
    int s[8]; float a[8]; unsigned v[8];
    #pragma unroll
    for (int u=0;u<8;u++) s[u] = csr[i+u];
    #pragma unroll
    for (int u=0;u<8;u++) a[u] = aS[s[u]*H1+h];
    #pragma unroll
    for (int u=0;u<8;u++) v[u] = *(const unsigned*)&h1b[(size_t)s[u]*D1 + c];
    #pragma unroll
    for (int u=0;u<8;u++){
      float pp = __expf(lrelu(a[u]+ad));
      d += pp; acc0 += pp*bf_lo(v[u]); acc1 += pp*bf_hi(v[u]);
    }
  }
  for (; i < e; ++i){
    int s = csr[i];
    float pp = __expf(lrelu(aS[s*H1+h] + ad));
    unsigned vv = *(const unsigned*)&h1b[(size_t)s*D1 + c];
    d += pp; acc0 += pp*bf_lo(vv); acc1 += pp*bf_hi(vv);
  }
  float inv = 1.f/d;
  float o0 = acc0*inv + b1[c];
  float o1 = acc1*inv + b1[c+1];
  x2[(size_t)n*D1+c]   = elu(o0);
  x2[(size_t)n*D1+c+1] = elu(o1);
}

// ---------------- GEMM2: h2 = x2 @ W2, fused attention dots ----------------
__global__ __launch_bounds__(256) void gemm2_k(const float* __restrict__ x2, const float* __restrict__ W2,
    const float* __restrict__ attS2, const float* __restrict__ attD2,
    float* __restrict__ h2, float* __restrict__ aS2, float* __restrict__ aD2, int N){
  __shared__ float Ws[128*D2];     // 20 KB
  __shared__ float Xs[32][129];    // 16.5 KB, padded
  int tid = threadIdx.x;
  for (int i = tid; i < 128*D2; i += 256) Ws[i] = W2[i];
  int r0 = blockIdx.x*32;
  for (int i = tid; i < 32*128; i += 256){
    int r = i >> 7, c = i & 127;
    Xs[r][c] = (r0 + r < N) ? x2[(size_t)(r0+r)*D1 + c] : 0.f;
  }
  __syncthreads();
  int r = tid >> 3, g = tid & 7;   // r: 0..31 row, g: 0..7 col-group (5 cols each)
  float acc[5] = {0.f,0.f,0.f,0.f,0.f};
  for (int k = 0; k < 128; ++k){
    float xv = Xs[r][k];
    #pragma unroll
    for (int j=0;j<5;j++) acc[j] += xv * Ws[k*D2 + g*5 + j];
  }
  int row = r0 + r;
  float pS = 0.f, pD = 0.f;
  #pragma unroll
  for (int j=0;j<5;j++){ pS += acc[j]*attS2[g*5+j]; pD += acc[j]*attD2[g*5+j]; }
  #pragma unroll
  for (int o=4;o>0;o>>=1){ pS += __shfl_down(pS,o,8); pD += __shfl_down(pD,o,8); }
  if (row < N){
    #pragma unroll
    for (int j=0;j<5;j++) h2[(size_t)row*D2 + g*5 + j] = acc[j];
    if (g == 0){ aS2[row] = pS; aD2[row] = pD; }
  }
}

// ---------------- node2: softmax aggregation, 8-deep gather pipeline, inline exp ----------------
__global__ __launch_bounds__(64) void node2_k(const float* __restrict__ h2,
    const float* __restrict__ aS2, const float* __restrict__ aD2,
    const int* __restrict__ off, const int* __restrict__ csr,
    const float* __restrict__ b2, float* __restrict__ out, int N){
  int n = blockIdx.x;
  int lane = threadIdx.x;
  bool act = lane < 20;
  int c = lane*2;
  float ad = aD2[n];
  float ps = __expf(lrelu(aS2[n] + ad));   // self loop
  float d = ps;
  float acc0 = 0.f, acc1 = 0.f;
  if (act){ float2 v = *(const float2*)&h2[(size_t)n*D2 + c]; acc0 = ps*v.x; acc1 = ps*v.y; }
  int i = off[n], e = off[n+1];
  for (; i+8 <= e; i += 8){
    int s[8]; float a[8]; float2 v[8];
    #pragma unroll
    for (int u=0;u<8;u++) s[u] = csr[i+u];
    #pragma unroll
    for (int u=0;u<8;u++) a[u] = aS2[s[u]];
    if (act){
      #pragma unroll
      for (int u=0;u<8;u++) v[u] = *(const float2*)&h2[(size_t)s[u]*D2 + c];
    } else {
      #pragma unroll
      for (int u=0;u<8;u++) v[u] = make_float2(0.f,0.f);
    }
    #pragma unroll
    for (int u=0;u<8;u++){
      float pp = __expf(lrelu(a[u]+ad));
      d += pp; acc0 += pp*v[u].x; acc1 += pp*v[u].y;
    }
  }
  for (; i < e; ++i){
    int s = csr[i];
    float pp = __expf(lrelu(aS2[s] + ad));
    d += pp;
    if (act){
      float2 vv = *(const float2*)&h2[(size_t)s*D2 + c];
      acc0 += pp*vv.x; acc1 += pp*vv.y;
    }
  }
  if (act){
    float inv = 1.f/d;
    out[(size_t)n*D2 + c]     = acc0*inv + b2[c];
    out[(size_t)n*D2 + c + 1] = acc1*inv + b2[c+1];
  }
}

extern "C" void kernel_launch(void* const* d_in, const int* in_sizes, int n_in,
                              void* d_out, int out_size, void* d_ws, size_t ws_size,
                              hipStream_t stream){
  const float* x     = (const float*)d_in[0];
  const int*   ei    = (const int*)d_in[1];
  const float* W1    = (const float*)d_in[2];
  const float* attS1 = (const float*)d_in[3];
  const float* attD1 = (const float*)d_in[4];
  const float* b1    = (const float*)d_in[5];
  const float* W2    = (const float*)d_in[6];
  const float* attS2 = (const float*)d_in[7];
  const float* attD2 = (const float*)d_in[8];
  const float* b2    = (const float*)d_in[9];
  float* out = (float*)d_out;

  int N = in_sizes[0] / FIN;   // 50000
  int E = in_sizes[1] / 2;     // 1600000
  const int* src = ei;
  const int* dst = ei + E;

  char* ws = (char*)d_ws;
  size_t o = 0;
  auto alloc = [&](size_t bytes) -> void* {
    void* p = ws + o;
    o += (bytes + 255) & ~size_t(255);
    return p;
  };
  unsigned short* h1b = (unsigned short*)alloc((size_t)N*D1*sizeof(unsigned short));
  float* x2    = (float*)alloc((size_t)N*D1*sizeof(float));
  float* h2    = (float*)alloc((size_t)N*D2*sizeof(float));
  float* aS1   = (float*)alloc((size_t)N*H1*sizeof(float));
  float* aD1   = (float*)alloc((size_t)N*H1*sizeof(float));
  float* aS2   = (float*)alloc((size_t)N*sizeof(float));
  float* aD2   = (float*)alloc((size_t)N*sizeof(float));
  int*   off   = (int*)alloc((size_t)(N+1)*sizeof(int));
  int*   cur   = (int*)alloc((size_t)N*sizeof(int));
  int*   csr   = (int*)alloc((size_t)E*sizeof(int));

  hipMemsetAsync(off, 0, (size_t)(N+1)*sizeof(int), stream);
  hist_k<<<(E+255)/256, 256, 0, stream>>>(dst, E, off);
  scan_k<<<1, 1024, 0, stream>>>(off, cur, N);
  scatter_mp<<<2048, 256, 0, stream>>>(src, dst, E, cur, csr, N);
  gemm1_k<<<(N+127)/128, 256, 0, stream>>>(x, W1, attS1, attD1, h1b, aS1, aD1, N);
  node1_k<<<N, 64, 0, stream>>>(h1b, aS1, aD1, off, csr, b1, x2, N);
  gemm2_k<<<(N+31)/32, 256, 0, stream>>>(x2, W2, attS2, attD2, h2, aS2, aD2, N);
  node2_k<<<N, 64, 0, stream>>>(h2, aS2, aD2, off, csr, b2, out, N);
}

// Round 6
// 267.705 us; speedup vs baseline: 2.9510x; 1.9100x over previous
//
#include <hip/hip_runtime.h>

#define FIN 256
#define H1 8
#define C1 16
#define D1 128   // H1*C1
#define D2 40

#define BW_LOG 9
#define BWIDTH 512           // nodes per bucket
#define B1 512               // phase-1 blocks

static __device__ __forceinline__ float lrelu(float x){ return fmaxf(x, 0.2f*x); }
static __device__ __forceinline__ float elu(float x){ return x > 0.f ? x : __expf(x) - 1.f; }
static __device__ __forceinline__ unsigned short f2bf(float f){      // RNE bf16
  unsigned u = __float_as_uint(f);
  return (unsigned short)((u + 0x7fffu + ((u >> 16) & 1u)) >> 16);
}
static __device__ __forceinline__ float bf_lo(unsigned v){ return __uint_as_float(v << 16); }
static __device__ __forceinline__ float bf_hi(unsigned v){ return __uint_as_float(v & 0xffff0000u); }

// ---------------- CSR build: deterministic bucket sort ----------------
// p1count: per-block histogram over NB buckets (bucket = dst >> BW_LOG)
__global__ __launch_bounds__(256) void p1count_k(const int* __restrict__ dst, int E, int NB,
                                                 int* __restrict__ blockHist){
  extern __shared__ int hist[];          // NB ints
  int blk = blockIdx.x, t = threadIdx.x;
  for (int i = t; i < NB; i += 256) hist[i] = 0;
  __syncthreads();
  int CH = (E + B1 - 1) / B1;
  int lo = blk*CH, hi = min(E, lo + CH);
  for (int i = lo + t; i < hi; i += 256)
    atomicAdd(&hist[dst[i] >> BW_LOG], 1);
  __syncthreads();
  for (int b = t; b < NB; b += 256) blockHist[b*B1 + blk] = hist[b];
}

// bscan: per-bucket exclusive scan over the B1 blocks
__global__ __launch_bounds__(B1) void bscan_k(const int* __restrict__ blockHist,
                                              int* __restrict__ wOff, int* __restrict__ bucketCnt){
  __shared__ int s[B1];
  int b = blockIdx.x, t = threadIdx.x;
  int v = blockHist[b*B1 + t];
  s[t] = v; __syncthreads();
  for (int o = 1; o < B1; o <<= 1){
    int u = (t >= o) ? s[t-o] : 0;
    __syncthreads();
    s[t] += u;
    __syncthreads();
  }
  wOff[b*B1 + t] = s[t] - v;             // exclusive
  if (t == B1-1) bucketCnt[b] = s[t];
}

// tscan: scan bucket counts -> bucketStart; also off[N] = E
__global__ void tscan_k(const int* __restrict__ bucketCnt, int NB,
                        int* __restrict__ bucketStart, int* __restrict__ off, int N){
  if (threadIdx.x == 0 && blockIdx.x == 0){
    int run = 0;
    for (int b = 0; b < NB; ++b){ bucketStart[b] = run; run += bucketCnt[b]; }
    bucketStart[NB] = run;
    off[N] = run;
  }
}

// p1scatter: append packed (src<<BW_LOG | dstLocal) into per-(block,bucket) runs
__global__ __launch_bounds__(256) void p1scatter_k(const int* __restrict__ src, const int* __restrict__ dst,
                                                   int E, int NB,
                                                   const int* __restrict__ bucketStart,
                                                   const int* __restrict__ wOff,
                                                   int* __restrict__ bucketEdges){
  extern __shared__ int curs[];          // NB ints
  int blk = blockIdx.x, t = threadIdx.x;
  for (int b = t; b < NB; b += 256) curs[b] = bucketStart[b] + wOff[b*B1 + blk];
  __syncthreads();
  int CH = (E + B1 - 1) / B1;
  int lo = blk*CH, hi = min(E, lo + CH);
  for (int i = lo + t; i < hi; i += 256){
    int dd = dst[i];
    int b = dd >> BW_LOG;
    int pos = atomicAdd(&curs[b], 1);
    bucketEdges[pos] = (src[i] << BW_LOG) | (dd & (BWIDTH-1));
  }
}

// p2: per-bucket deg/off/csr build. One block per bucket.
__global__ __launch_bounds__(BWIDTH) void p2_k(const int* __restrict__ bucketEdges,
                                               const int* __restrict__ bucketStart,
                                               int* __restrict__ off, int* __restrict__ csr, int N){
  __shared__ int deg[BWIDTH];
  __shared__ int s[BWIDTH];
  __shared__ int cur[BWIDTH];
  int b = blockIdx.x, t = threadIdx.x;
  int e0 = bucketStart[b], e1 = bucketStart[b+1];
  deg[t] = 0;
  __syncthreads();
  for (int i = e0 + t; i < e1; i += BWIDTH)
    atomicAdd(&deg[bucketEdges[i] & (BWIDTH-1)], 1);
  __syncthreads();
  int v = deg[t];
  s[t] = v; __syncthreads();
  for (int o = 1; o < BWIDTH; o <<= 1){
    int u = (t >= o) ? s[t-o] : 0;
    __syncthreads();
    s[t] += u;
    __syncthreads();
  }
  int excl = s[t] - v;
  int node = b*BWIDTH + t;
  if (node < N) off[node] = e0 + excl;
  cur[t] = excl;
  __syncthreads();
  for (int i = e0 + t; i < e1; i += BWIDTH){
    int pk = bucketEdges[i];
    int p = atomicAdd(&cur[pk & (BWIDTH-1)], 1);
    csr[e0 + p] = pk >> BW_LOG;
  }
}

// ---------------- GEMM1: h1(bf16) = x @ W1 (128x128 tile, 8x8/thread), fused attention dots ----------------
__global__ __launch_bounds__(256) void gemm1_k(const float* __restrict__ x, const float* __restrict__ W,
    const float* __restrict__ attS, const float* __restrict__ attD,
    unsigned short* __restrict__ h1b, float* __restrict__ aS, float* __restrict__ aD, int N){
  __shared__ float As[16][128];   // [k][m] 8KB
  __shared__ float Bs[16][128];   // [k][n] 8KB
  int tid = threadIdx.x;
  int tx = tid & 15, ty = tid >> 4;
  int m0 = blockIdx.x * 128;
  float acc[8][8];
  #pragma unroll
  for (int i=0;i<8;i++)
    #pragma unroll
    for (int j=0;j<8;j++) acc[i][j]=0.f;

  for (int k0 = 0; k0 < FIN; k0 += 16){
    #pragma unroll
    for (int l=0;l<2;l++){
      int fidx = tid + l*256;          // 0..511 over 128 rows x 4 float4-cols
      int r = fidx >> 2, cq = fidx & 3;
      int gr = m0 + r;
      float4 v = (gr < N) ? *(const float4*)&x[(size_t)gr*FIN + k0 + cq*4]
                          : make_float4(0.f,0.f,0.f,0.f);
      As[cq*4+0][r] = v.x; As[cq*4+1][r] = v.y; As[cq*4+2][r] = v.z; As[cq*4+3][r] = v.w;
    }
    #pragma unroll
    for (int l=0;l<2;l++){
      int fidx = tid + l*256;          // 0..511 over 16 rows x 32 float4-cols
      int r = fidx >> 5, c4 = fidx & 31;
      *(float4*)&Bs[r][c4*4] = *(const float4*)&W[(size_t)(k0+r)*D1 + c4*4];
    }
    __syncthreads();
    #pragma unroll
    for (int k=0;k<16;k++){
      float a[8], b[8];
      *(float4*)&a[0] = *(const float4*)&As[k][ty*8];
      *(float4*)&a[4] = *(const float4*)&As[k][ty*8+4];
      *(float4*)&b[0] = *(const float4*)&Bs[k][tx*8];
      *(float4*)&b[4] = *(const float4*)&Bs[k][tx*8+4];
      #pragma unroll
      for (int i=0;i<8;i++)
        #pragma unroll
        for (int j=0;j<8;j++) acc[i][j] += a[i]*b[j];
    }
    __syncthreads();
  }

  int h = tx >> 1;                 // head of this 8-col group
  int sub = (tx & 1) * 8;          // which half of the head's 16 channels
  #pragma unroll
  for (int i=0;i<8;i++){
    int r = m0 + ty*8 + i;
    if (r < N){
      unsigned pk0 = (unsigned)f2bf(acc[i][0]) | ((unsigned)f2bf(acc[i][1]) << 16);
      unsigned pk1 = (unsigned)f2bf(acc[i][2]) | ((unsigned)f2bf(acc[i][3]) << 16);
      unsigned pk2 = (unsigned)f2bf(acc[i][4]) | ((unsigned)f2bf(acc[i][5]) << 16);
      unsigned pk3 = (unsigned)f2bf(acc[i][6]) | ((unsigned)f2bf(acc[i][7]) << 16);
      *(uint4*)&h1b[(size_t)r*D1 + tx*8] = make_uint4(pk0,pk1,pk2,pk3);
      float pS=0.f, pD=0.f;
      #pragma unroll
      for (int j=0;j<8;j++){
        pS += acc[i][j]*attS[h*C1+sub+j];
        pD += acc[i][j]*attD[h*C1+sub+j];
      }
      pS += __shfl_xor(pS,1);
      pD += __shfl_xor(pD,1);
      if ((tx & 1) == 0){ aS[r*H1+h] = pS; aD[r*H1+h] = pD; }
    }
  }
}

// ---------------- node1: softmax aggregation over bf16 h1, 8-deep gather pipeline ----------------
__global__ __launch_bounds__(64) void node1_k(const unsigned short* __restrict__ h1b,
    const float* __restrict__ aS, const float* __restrict__ aD,
    const int* __restrict__ off, const int* __restrict__ csr,
    const float* __restrict__ b1, float* __restrict__ x2, int N){
  int n = blockIdx.x;
  int lane = threadIdx.x;
  int c = lane*2;                 // channels c, c+1
  int h = lane >> 3;              // head = c/16
  float ad = aD[n*H1+h];
  float p = __expf(lrelu(aS[n*H1+h] + ad));   // self loop
  float d = p;
  unsigned hv = *(const unsigned*)&h1b[(size_t)n*D1 + c];
  float acc0 = p*bf_lo(hv), acc1 = p*bf_hi(hv);
  int i = off[n], e = off[n+1];
  for (; i+8 <= e; i += 8){
    int s[8]; float a[8]; unsigned v[8];
    #pragma unroll
    for (int u=0;u<8;u++) s[u] = csr[i+u];
    #pragma unroll
    for (int u=0;u<8;u++) a[u] = aS[s[u]*H1+h];
    #pragma unroll
    for (int u=0;u<8;u++) v[u] = *(const unsigned*)&h1b[(size_t)s[u]*D1 + c];
    #pragma unroll
    for (int u=0;u<8;u++){
      float pp = __expf(lrelu(a[u]+ad));
      d += pp; acc0 += pp*bf_lo(v[u]); acc1 += pp*bf_hi(v[u]);
    }
  }
  for (; i < e; ++i){
    int s = csr[i];
    float pp = __expf(lrelu(aS[s*H1+h] + ad));
    unsigned vv = *(const unsigned*)&h1b[(size_t)s*D1 + c];
    d += pp; acc0 += pp*bf_lo(vv); acc1 += pp*bf_hi(vv);
  }
  float inv = 1.f/d;
  float o0 = acc0*inv + b1[c];
  float o1 = acc1*inv + b1[c+1];
  x2[(size_t)n*D1+c]   = elu(o0);
  x2[(size_t)n*D1+c+1] = elu(o1);
}

// ---------------- GEMM2: h2 = x2 @ W2, fused attention dots ----------------
__global__ __launch_bounds__(256) void gemm2_k(const float* __restrict__ x2, const float* __restrict__ W2,
    const float* __restrict__ attS2, const float* __restrict__ attD2,
    float* __restrict__ h2, float* __restrict__ aS2, float* __restrict__ aD2, int N){
  __shared__ float Ws[128*D2];     // 20 KB
  __shared__ float Xs[32][129];    // 16.5 KB, padded
  int tid = threadIdx.x;
  for (int i = tid; i < 128*D2; i += 256) Ws[i] = W2[i];
  int r0 = blockIdx.x*32;
  for (int i = tid; i < 32*128; i += 256){
    int r = i >> 7, c = i & 127;
    Xs[r][c] = (r0 + r < N) ? x2[(size_t)(r0+r)*D1 + c] : 0.f;
  }
  __syncthreads();
  int r = tid >> 3, g = tid & 7;   // r: 0..31 row, g: 0..7 col-group (5 cols each)
  float acc[5] = {0.f,0.f,0.f,0.f,0.f};
  for (int k = 0; k < 128; ++k){
    float xv = Xs[r][k];
    #pragma unroll
    for (int j=0;j<5;j++) acc[j] += xv * Ws[k*D2 + g*5 + j];
  }
  int row = r0 + r;
  float pS = 0.f, pD = 0.f;
  #pragma unroll
  for (int j=0;j<5;j++){ pS += acc[j]*attS2[g*5+j]; pD += acc[j]*attD2[g*5+j]; }
  #pragma unroll
  for (int o=4;o>0;o>>=1){ pS += __shfl_down(pS,o,8); pD += __shfl_down(pD,o,8); }
  if (row < N){
    #pragma unroll
    for (int j=0;j<5;j++) h2[(size_t)row*D2 + g*5 + j] = acc[j];
    if (g == 0){ aS2[row] = pS; aD2[row] = pD; }
  }
}

// ---------------- node2: softmax aggregation, 8-deep gather pipeline, inline exp ----------------
__global__ __launch_bounds__(64) void node2_k(const float* __restrict__ h2,
    const float* __restrict__ aS2, const float* __restrict__ aD2,
    const int* __restrict__ off, const int* __restrict__ csr,
    const float* __restrict__ b2, float* __restrict__ out, int N){
  int n = blockIdx.x;
  int lane = threadIdx.x;
  bool act = lane < 20;
  int c = lane*2;
  float ad = aD2[n];
  float ps = __expf(lrelu(aS2[n] + ad));   // self loop
  float d = ps;
  float acc0 = 0.f, acc1 = 0.f;
  if (act){ float2 v = *(const float2*)&h2[(size_t)n*D2 + c]; acc0 = ps*v.x; acc1 = ps*v.y; }
  int i = off[n], e = off[n+1];
  for (; i+8 <= e; i += 8){
    int s[8]; float a[8]; float2 v[8];
    #pragma unroll
    for (int u=0;u<8;u++) s[u] = csr[i+u];
    #pragma unroll
    for (int u=0;u<8;u++) a[u] = aS2[s[u]];
    if (act){
      #pragma unroll
      for (int u=0;u<8;u++) v[u] = *(const float2*)&h2[(size_t)s[u]*D2 + c];
    } else {
      #pragma unroll
      for (int u=0;u<8;u++) v[u] = make_float2(0.f,0.f);
    }
    #pragma unroll
    for (int u=0;u<8;u++){
      float pp = __expf(lrelu(a[u]+ad));
      d += pp; acc0 += pp*v[u].x; acc1 += pp*v[u].y;
    }
  }
  for (; i < e; ++i){
    int s = csr[i];
    float pp = __expf(lrelu(aS2[s] + ad));
    d += pp;
    if (act){
      float2 vv = *(const float2*)&h2[(size_t)s*D2 + c];
      acc0 += pp*vv.x; acc1 += pp*vv.y;
    }
  }
  if (act){
    float inv = 1.f/d;
    out[(size_t)n*D2 + c]     = acc0*inv + b2[c];
    out[(size_t)n*D2 + c + 1] = acc1*inv + b2[c+1];
  }
}

extern "C" void kernel_launch(void* const* d_in, const int* in_sizes, int n_in,
                              void* d_out, int out_size, void* d_ws, size_t ws_size,
                              hipStream_t stream){
  const float* x     = (const float*)d_in[0];
  const int*   ei    = (const int*)d_in[1];
  const float* W1    = (const float*)d_in[2];
  const float* attS1 = (const float*)d_in[3];
  const float* attD1 = (const float*)d_in[4];
  const float* b1    = (const float*)d_in[5];
  const float* W2    = (const float*)d_in[6];
  const float* attS2 = (const float*)d_in[7];
  const float* attD2 = (const float*)d_in[8];
  const float* b2    = (const float*)d_in[9];
  float* out = (float*)d_out;

  int N = in_sizes[0] / FIN;   // 50000
  int E = in_sizes[1] / 2;     // 1600000
  const int* src = ei;
  const int* dst = ei + E;
  int NB = (N + BWIDTH - 1) >> BW_LOG;    // 98

  char* ws = (char*)d_ws;
  size_t o = 0;
  auto alloc = [&](size_t bytes) -> void* {
    void* p = ws + o;
    o += (bytes + 255) & ~size_t(255);
    return p;
  };
  unsigned short* h1b = (unsigned short*)alloc((size_t)N*D1*sizeof(unsigned short));
  float* x2    = (float*)alloc((size_t)N*D1*sizeof(float));
  float* h2    = (float*)alloc((size_t)N*D2*sizeof(float));
  float* aS1   = (float*)alloc((size_t)N*H1*sizeof(float));
  float* aD1   = (float*)alloc((size_t)N*H1*sizeof(float));
  float* aS2   = (float*)alloc((size_t)N*sizeof(float));
  float* aD2   = (float*)alloc((size_t)N*sizeof(float));
  int*   off   = (int*)alloc((size_t)(N+1)*sizeof(int));
  int*   csr   = (int*)alloc((size_t)E*sizeof(int));
  int*   blockHist   = (int*)alloc((size_t)NB*B1*sizeof(int));
  int*   wOff        = (int*)alloc((size_t)NB*B1*sizeof(int));
  int*   bucketCnt   = (int*)alloc((size_t)NB*sizeof(int));
  int*   bucketStart = (int*)alloc((size_t)(NB+1)*sizeof(int));
  int*   bucketEdges = (int*)alloc((size_t)E*sizeof(int));

  size_t smNB = (size_t)NB*sizeof(int);
  p1count_k<<<B1, 256, smNB, stream>>>(dst, E, NB, blockHist);
  bscan_k<<<NB, B1, 0, stream>>>(blockHist, wOff, bucketCnt);
  tscan_k<<<1, 64, 0, stream>>>(bucketCnt, NB, bucketStart, off, N);
  p1scatter_k<<<B1, 256, smNB, stream>>>(src, dst, E, NB, bucketStart, wOff, bucketEdges);
  p2_k<<<NB, BWIDTH, 0, stream>>>(bucketEdges, bucketStart, off, csr, N);
  gemm1_k<<<(N+127)/128, 256, 0, stream>>>(x, W1, attS1, attD1, h1b, aS1, aD1, N);
  node1_k<<<N, 64, 0, stream>>>(h1b, aS1, aD1, off, csr, b1, x2, N);
  gemm2_k<<<(N+31)/32, 256, 0, stream>>>(x2, W2, attS2, attD2, h2, aS2, aD2, N);
  node2_k<<<N, 64, 0, stream>>>(h2, aS2, aD2, off, csr, b2, out, N);
}

// Round 7
// 249.779 us; speedup vs baseline: 3.1628x; 1.0718x over previous
//
#include <hip/hip_runtime.h>

#define FIN 256
#define H1 8
#define C1 16
#define D1 128   // H1*C1
#define D2 40

#define BW_LOG 9
#define BWIDTH 512           // nodes per bucket
#define B1 512               // phase-1 blocks

typedef float f32x4 __attribute__((ext_vector_type(4)));
typedef short bf16x8 __attribute__((ext_vector_type(8)));

static __device__ __forceinline__ float lrelu(float x){ return fmaxf(x, 0.2f*x); }
static __device__ __forceinline__ float elu(float x){ return x > 0.f ? x : __expf(x) - 1.f; }
static __device__ __forceinline__ unsigned short f2bf(float f){      // RNE bf16
  unsigned u = __float_as_uint(f);
  return (unsigned short)((u + 0x7fffu + ((u >> 16) & 1u)) >> 16);
}
static __device__ __forceinline__ float bf_lo(unsigned v){ return __uint_as_float(v << 16); }
static __device__ __forceinline__ float bf_hi(unsigned v){ return __uint_as_float(v & 0xffff0000u); }
static __device__ __forceinline__ bf16x8 pack_bf8(float4 a, float4 b){
  bf16x8 r;
  r[0]=(short)f2bf(a.x); r[1]=(short)f2bf(a.y); r[2]=(short)f2bf(a.z); r[3]=(short)f2bf(a.w);
  r[4]=(short)f2bf(b.x); r[5]=(short)f2bf(b.y); r[6]=(short)f2bf(b.z); r[7]=(short)f2bf(b.w);
  return r;
}

// ---------------- CSR build: deterministic bucket sort ----------------
__global__ __launch_bounds__(256) void p1count_k(const int* __restrict__ dst, int E, int NB,
                                                 int* __restrict__ blockHist){
  extern __shared__ int hist[];
  int blk = blockIdx.x, t = threadIdx.x;
  for (int i = t; i < NB; i += 256) hist[i] = 0;
  __syncthreads();
  int CH = (E + B1 - 1) / B1;
  int lo = blk*CH, hi = min(E, lo + CH);
  for (int i = lo + t; i < hi; i += 256)
    atomicAdd(&hist[dst[i] >> BW_LOG], 1);
  __syncthreads();
  for (int b = t; b < NB; b += 256) blockHist[b*B1 + blk] = hist[b];
}

__global__ __launch_bounds__(B1) void bscan_k(const int* __restrict__ blockHist,
                                              int* __restrict__ wOff, int* __restrict__ bucketCnt){
  __shared__ int s[B1];
  int b = blockIdx.x, t = threadIdx.x;
  int v = blockHist[b*B1 + t];
  s[t] = v; __syncthreads();
  for (int o = 1; o < B1; o <<= 1){
    int u = (t >= o) ? s[t-o] : 0;
    __syncthreads();
    s[t] += u;
    __syncthreads();
  }
  wOff[b*B1 + t] = s[t] - v;
  if (t == B1-1) bucketCnt[b] = s[t];
}

__global__ void tscan_k(const int* __restrict__ bucketCnt, int NB,
                        int* __restrict__ bucketStart, int* __restrict__ off, int N){
  if (threadIdx.x == 0 && blockIdx.x == 0){
    int run = 0;
    for (int b = 0; b < NB; ++b){ bucketStart[b] = run; run += bucketCnt[b]; }
    bucketStart[NB] = run;
    off[N] = run;
  }
}

__global__ __launch_bounds__(256) void p1scatter_k(const int* __restrict__ src, const int* __restrict__ dst,
                                                   int E, int NB,
                                                   const int* __restrict__ bucketStart,
                                                   const int* __restrict__ wOff,
                                                   int* __restrict__ bucketEdges){
  extern __shared__ int curs[];
  int blk = blockIdx.x, t = threadIdx.x;
  for (int b = t; b < NB; b += 256) curs[b] = bucketStart[b] + wOff[b*B1 + blk];
  __syncthreads();
  int CH = (E + B1 - 1) / B1;
  int lo = blk*CH, hi = min(E, lo + CH);
  for (int i = lo + t; i < hi; i += 256){
    int dd = dst[i];
    int b = dd >> BW_LOG;
    int pos = atomicAdd(&curs[b], 1);
    bucketEdges[pos] = (src[i] << BW_LOG) | (dd & (BWIDTH-1));
  }
}

__global__ __launch_bounds__(BWIDTH) void p2_k(const int* __restrict__ bucketEdges,
                                               const int* __restrict__ bucketStart,
                                               int* __restrict__ off, int* __restrict__ csr, int N){
  __shared__ int deg[BWIDTH];
  __shared__ int s[BWIDTH];
  __shared__ int cur[BWIDTH];
  int b = blockIdx.x, t = threadIdx.x;
  int e0 = bucketStart[b], e1 = bucketStart[b+1];
  deg[t] = 0;
  __syncthreads();
  for (int i = e0 + t; i < e1; i += BWIDTH)
    atomicAdd(&deg[bucketEdges[i] & (BWIDTH-1)], 1);
  __syncthreads();
  int v = deg[t];
  s[t] = v; __syncthreads();
  for (int o = 1; o < BWIDTH; o <<= 1){
    int u = (t >= o) ? s[t-o] : 0;
    __syncthreads();
    s[t] += u;
    __syncthreads();
  }
  int excl = s[t] - v;
  int node = b*BWIDTH + t;
  if (node < N) off[node] = e0 + excl;
  cur[t] = excl;
  __syncthreads();
  for (int i = e0 + t; i < e1; i += BWIDTH){
    int pk = bucketEdges[i];
    int p = atomicAdd(&cur[pk & (BWIDTH-1)], 1);
    csr[e0 + p] = pk >> BW_LOG;
  }
}

// ---------------- W1T: [256][128] fp32 -> [128][256] bf16 ----------------
__global__ __launch_bounds__(256) void wt_k(const float* __restrict__ W, unsigned short* __restrict__ WT){
  int n = blockIdx.x;       // 0..127
  int k = threadIdx.x;      // 0..255
  WT[n*FIN + k] = f2bf(W[(size_t)k*D1 + n]);
}

// ---------------- GEMM1 via MFMA: h1b(bf16) = x @ W1, fused attention dots ----------------
// Block: 256 thr = 4 waves (2x2). Block tile 64 rows x 128 cols. Wave tile 32x64.
// No LDS: A-frags loaded direct from x (fp32->bf16 in-reg), B-frags from W1T bf16 (L2-resident).
__global__ __launch_bounds__(256) void gemm1_mfma(const float* __restrict__ x,
    const unsigned short* __restrict__ W1T,
    const float* __restrict__ attS, const float* __restrict__ attD,
    unsigned short* __restrict__ h1b, float* __restrict__ aS, float* __restrict__ aD, int N){
  int tid = threadIdx.x;
  int w = tid >> 6, lane = tid & 63;
  int lr = lane & 15, lg = lane >> 4;
  int wm = w >> 1, wn = w & 1;
  int m0 = blockIdx.x * 64;

  int rowA[2];
  #pragma unroll
  for (int mi=0;mi<2;mi++){
    int r = m0 + wm*32 + mi*16 + lr;
    rowA[mi] = (r < N) ? r : (N-1);
  }

  f32x4 acc[2][4];
  #pragma unroll
  for (int mi=0;mi<2;mi++)
    #pragma unroll
    for (int ni=0;ni<4;ni++) acc[mi][ni] = (f32x4){0.f,0.f,0.f,0.f};

  #pragma unroll
  for (int ks = 0; ks < 8; ++ks){
    int k0 = ks*32 + lg*8;
    bf16x8 a[2], b[4];
    #pragma unroll
    for (int mi=0;mi<2;mi++){
      const float* px = x + (size_t)rowA[mi]*FIN + k0;
      float4 v0 = *(const float4*)px;
      float4 v1 = *(const float4*)(px+4);
      a[mi] = pack_bf8(v0, v1);
    }
    #pragma unroll
    for (int ni=0;ni<4;ni++){
      int col = wn*64 + ni*16 + lr;
      b[ni] = *(const bf16x8*)(W1T + (size_t)col*FIN + k0);
    }
    #pragma unroll
    for (int mi=0;mi<2;mi++)
      #pragma unroll
      for (int ni=0;ni<4;ni++)
        acc[mi][ni] = __builtin_amdgcn_mfma_f32_16x16x32_bf16(a[mi], b[ni], acc[mi][ni], 0, 0, 0);
  }

  // epilogue: store bf16 h1, fused attention dots (one head per 16-col frag)
  #pragma unroll
  for (int mi=0;mi<2;mi++){
    #pragma unroll
    for (int ni=0;ni<4;ni++){
      int h = wn*4 + ni;
      int col = wn*64 + ni*16 + lr;
      float sS = attS[h*C1 + lr], sD = attD[h*C1 + lr];
      #pragma unroll
      for (int i=0;i<4;i++){
        int row = m0 + wm*32 + mi*16 + 4*lg + i;
        float v = acc[mi][ni][i];
        float pS = v*sS, pD = v*sD;
        pS += __shfl_xor(pS, 1); pD += __shfl_xor(pD, 1);
        pS += __shfl_xor(pS, 2); pD += __shfl_xor(pD, 2);
        pS += __shfl_xor(pS, 4); pD += __shfl_xor(pD, 4);
        pS += __shfl_xor(pS, 8); pD += __shfl_xor(pD, 8);
        if (row < N){
          h1b[(size_t)row*D1 + col] = f2bf(v);
          if (lr == 0){ aS[row*H1 + h] = pS; aD[row*H1 + h] = pD; }
        }
      }
    }
  }
}

// ---------------- node1: softmax aggregation over bf16 h1, 8-deep gather pipeline ----------------
__global__ __launch_bounds__(64) void node1_k(const unsigned short* __restrict__ h1b,
    const float* __restrict__ aS, const float* __restrict__ aD,
    const int* __restrict__ off, const int* __restrict__ csr,
    const float* __restrict__ b1, float* __restrict__ x2, int N){
  int n = blockIdx.x;
  int lane = threadIdx.x;
  int c = lane*2;                 // channels c, c+1
  int h = lane >> 3;              // head = c/16
  float ad = aD[n*H1+h];
  float p = __expf(lrelu(aS[n*H1+h] + ad));   // self loop
  float d = p;
  unsigned hv = *(const unsigned*)&h1b[(size_t)n*D1 + c];
  float acc0 = p*bf_lo(hv), acc1 = p*bf_hi(hv);
  int i = off[n], e = off[n+1];
  for (; i+8 <= e; i += 8){
    int s[8]; float a[8]; unsigned v[8];
    #pragma unroll
    for (int u=0;u<8;u++) s[u] = csr[i+u];
    #pragma unroll
    for (int u=0;u<8;u++) a[u] = aS[s[u]*H1+h];
    #pragma unroll
    for (int u=0;u<8;u++) v[u] = *(const unsigned*)&h1b[(size_t)s[u]*D1 + c];
    #pragma unroll
    for (int u=0;u<8;u++){
      float pp = __expf(lrelu(a[u]+ad));
      d += pp; acc0 += pp*bf_lo(v[u]); acc1 += pp*bf_hi(v[u]);
    }
  }
  for (; i < e; ++i){
    int s = csr[i];
    float pp = __expf(lrelu(aS[s*H1+h] + ad));
    unsigned vv = *(const unsigned*)&h1b[(size_t)s*D1 + c];
    d += pp; acc0 += pp*bf_lo(vv); acc1 += pp*bf_hi(vv);
  }
  float inv = 1.f/d;
  float o0 = acc0*inv + b1[c];
  float o1 = acc1*inv + b1[c+1];
  x2[(size_t)n*D1+c]   = elu(o0);
  x2[(size_t)n*D1+c+1] = elu(o1);
}

// ---------------- GEMM2: h2 = x2 @ W2, fused attention dots ----------------
__global__ __launch_bounds__(256) void gemm2_k(const float* __restrict__ x2, const float* __restrict__ W2,
    const float* __restrict__ attS2, const float* __restrict__ attD2,
    float* __restrict__ h2, float* __restrict__ aS2, float* __restrict__ aD2, int N){
  __shared__ float Ws[128*D2];     // 20 KB
  __shared__ float Xs[32][129];    // 16.5 KB, padded
  int tid = threadIdx.x;
  for (int i = tid; i < 128*D2; i += 256) Ws[i] = W2[i];
  int r0 = blockIdx.x*32;
  for (int i = tid; i < 32*128; i += 256){
    int r = i >> 7, c = i & 127;
    Xs[r][c] = (r0 + r < N) ? x2[(size_t)(r0+r)*D1 + c] : 0.f;
  }
  __syncthreads();
  int r = tid >> 3, g = tid & 7;
  float acc[5] = {0.f,0.f,0.f,0.f,0.f};
  for (int k = 0; k < 128; ++k){
    float xv = Xs[r][k];
    #pragma unroll
    for (int j=0;j<5;j++) acc[j] += xv * Ws[k*D2 + g*5 + j];
  }
  int row = r0 + r;
  float pS = 0.f, pD = 0.f;
  #pragma unroll
  for (int j=0;j<5;j++){ pS += acc[j]*attS2[g*5+j]; pD += acc[j]*attD2[g*5+j]; }
  #pragma unroll
  for (int o=4;o>0;o>>=1){ pS += __shfl_down(pS,o,8); pD += __shfl_down(pD,o,8); }
  if (row < N){
    #pragma unroll
    for (int j=0;j<5;j++) h2[(size_t)row*D2 + g*5 + j] = acc[j];
    if (g == 0){ aS2[row] = pS; aD2[row] = pD; }
  }
}

// ---------------- node2: softmax aggregation, 8-deep gather pipeline, inline exp ----------------
__global__ __launch_bounds__(64) void node2_k(const float* __restrict__ h2,
    const float* __restrict__ aS2, const float* __restrict__ aD2,
    const int* __restrict__ off, const int* __restrict__ csr,
    const float* __restrict__ b2, float* __restrict__ out, int N){
  int n = blockIdx.x;
  int lane = threadIdx.x;
  bool act = lane < 20;
  int c = lane*2;
  float ad = aD2[n];
  float ps = __expf(lrelu(aS2[n] + ad));   // self loop
  float d = ps;
  float acc0 = 0.f, acc1 = 0.f;
  if (act){ float2 v = *(const float2*)&h2[(size_t)n*D2 + c]; acc0 = ps*v.x; acc1 = ps*v.y; }
  int i = off[n], e = off[n+1];
  for (; i+8 <= e; i += 8){
    int s[8]; float a[8]; float2 v[8];
    #pragma unroll
    for (int u=0;u<8;u++) s[u] = csr[i+u];
    #pragma unroll
    for (int u=0;u<8;u++) a[u] = aS2[s[u]];
    if (act){
      #pragma unroll
      for (int u=0;u<8;u++) v[u] = *(const float2*)&h2[(size_t)s[u]*D2 + c];
    } else {
      #pragma unroll
      for (int u=0;u<8;u++) v[u] = make_float2(0.f,0.f);
    }
    #pragma unroll
    for (int u=0;u<8;u++){
      float pp = __expf(lrelu(a[u]+ad));
      d += pp; acc0 += pp*v[u].x; acc1 += pp*v[u].y;
    }
  }
  for (; i < e; ++i){
    int s = csr[i];
    float pp = __expf(lrelu(aS2[s] + ad));
    d += pp;
    if (act){
      float2 vv = *(const float2*)&h2[(size_t)s*D2 + c];
      acc0 += pp*vv.x; acc1 += pp*vv.y;
    }
  }
  if (act){
    float inv = 1.f/d;
    out[(size_t)n*D2 + c]     = acc0*inv + b2[c];
    out[(size_t)n*D2 + c + 1] = acc1*inv + b2[c+1];
  }
}

extern "C" void kernel_launch(void* const* d_in, const int* in_sizes, int n_in,
                              void* d_out, int out_size, void* d_ws, size_t ws_size,
                              hipStream_t stream){
  const float* x     = (const float*)d_in[0];
  const int*   ei    = (const int*)d_in[1];
  const float* W1    = (const float*)d_in[2];
  const float* attS1 = (const float*)d_in[3];
  const float* attD1 = (const float*)d_in[4];
  const float* b1    = (const float*)d_in[5];
  const float* W2    = (const float*)d_in[6];
  const float* attS2 = (const float*)d_in[7];
  const float* attD2 = (const float*)d_in[8];
  const float* b2    = (const float*)d_in[9];
  float* out = (float*)d_out;

  int N = in_sizes[0] / FIN;   // 50000
  int E = in_sizes[1] / 2;     // 1600000
  const int* src = ei;
  const int* dst = ei + E;
  int NB = (N + BWIDTH - 1) >> BW_LOG;    // 98

  char* ws = (char*)d_ws;
  size_t o = 0;
  auto alloc = [&](size_t bytes) -> void* {
    void* p = ws + o;
    o += (bytes + 255) & ~size_t(255);
    return p;
  };
  unsigned short* h1b = (unsigned short*)alloc((size_t)N*D1*sizeof(unsigned short));
  float* x2    = (float*)alloc((size_t)N*D1*sizeof(float));
  float* h2    = (float*)alloc((size_t)N*D2*sizeof(float));
  float* aS1   = (float*)alloc((size_t)N*H1*sizeof(float));
  float* aD1   = (float*)alloc((size_t)N*H1*sizeof(float));
  float* aS2   = (float*)alloc((size_t)N*sizeof(float));
  float* aD2   = (float*)alloc((size_t)N*sizeof(float));
  int*   off   = (int*)alloc((size_t)(N+1)*sizeof(int));
  int*   csr   = (int*)alloc((size_t)E*sizeof(int));
  int*   blockHist   = (int*)alloc((size_t)NB*B1*sizeof(int));
  int*   wOff        = (int*)alloc((size_t)NB*B1*sizeof(int));
  int*   bucketCnt   = (int*)alloc((size_t)NB*sizeof(int));
  int*   bucketStart = (int*)alloc((size_t)(NB+1)*sizeof(int));
  int*   bucketEdges = (int*)alloc((size_t)E*sizeof(int));
  unsigned short* W1T = (unsigned short*)alloc((size_t)D1*FIN*sizeof(unsigned short));

  size_t smNB = (size_t)NB*sizeof(int);
  p1count_k<<<B1, 256, smNB, stream>>>(dst, E, NB, blockHist);
  bscan_k<<<NB, B1, 0, stream>>>(blockHist, wOff, bucketCnt);
  tscan_k<<<1, 64, 0, stream>>>(bucketCnt, NB, bucketStart, off, N);
  p1scatter_k<<<B1, 256, smNB, stream>>>(src, dst, E, NB, bucketStart, wOff, bucketEdges);
  p2_k<<<NB, BWIDTH, 0, stream>>>(bucketEdges, bucketStart, off, csr, N);
  wt_k<<<D1, 256, 0, stream>>>(W1, W1T);
  gemm1_mfma<<<(N+63)/64, 256, 0, stream>>>(x, W1T, attS1, attD1, h1b, aS1, aD1, N);
  node1_k<<<N, 64, 0, stream>>>(h1b, aS1, aD1, off, csr, b1, x2, N);
  gemm2_k<<<(N+31)/32, 256, 0, stream>>>(x2, W2, attS2, attD2, h2, aS2, aD2, N);
  node2_k<<<N, 64, 0, stream>>>(h2, aS2, aD2, off, csr, b2, out, N);
}

// Round 8
// 234.447 us; speedup vs baseline: 3.3696x; 1.0654x over previous
//
#include <hip/hip_runtime.h>

#define FIN 256
#define H1 8
#define C1 16
#define D1 128   // H1*C1
#define D2 40
#define D2P 48

#define BW_LOG 9
#define BWIDTH 512           // nodes per bucket
#define B1 512               // phase-1 blocks

typedef float f32x4 __attribute__((ext_vector_type(4)));
typedef short bf16x8 __attribute__((ext_vector_type(8)));

static __device__ __forceinline__ float lrelu(float x){ return fmaxf(x, 0.2f*x); }
static __device__ __forceinline__ float elu(float x){ return x > 0.f ? x : __expf(x) - 1.f; }
static __device__ __forceinline__ unsigned short f2bf(float f){      // RNE bf16
  unsigned u = __float_as_uint(f);
  return (unsigned short)((u + 0x7fffu + ((u >> 16) & 1u)) >> 16);
}
static __device__ __forceinline__ float bf2f(unsigned short h){ return __uint_as_float(((unsigned)h) << 16); }
static __device__ __forceinline__ float bf_lo(unsigned v){ return __uint_as_float(v << 16); }
static __device__ __forceinline__ float bf_hi(unsigned v){ return __uint_as_float(v & 0xffff0000u); }
static __device__ __forceinline__ bf16x8 pack_bf8(float4 a, float4 b){
  bf16x8 r;
  r[0]=(short)f2bf(a.x); r[1]=(short)f2bf(a.y); r[2]=(short)f2bf(a.z); r[3]=(short)f2bf(a.w);
  r[4]=(short)f2bf(b.x); r[5]=(short)f2bf(b.y); r[6]=(short)f2bf(b.z); r[7]=(short)f2bf(b.w);
  return r;
}
static __device__ __forceinline__ void pack_hilo(const float* p, bf16x8& hi, bf16x8& lo){
  #pragma unroll
  for (int j=0;j<8;j++){
    float v = p[j];
    unsigned short h = f2bf(v);
    hi[j] = (short)h;
    lo[j] = (short)f2bf(v - bf2f(h));
  }
}

// ---------------- CSR build: deterministic bucket sort ----------------
__global__ __launch_bounds__(256) void p1count_k(const int* __restrict__ dst, int E, int NB,
                                                 int* __restrict__ blockHist){
  extern __shared__ int hist[];
  int blk = blockIdx.x, t = threadIdx.x;
  for (int i = t; i < NB; i += 256) hist[i] = 0;
  __syncthreads();
  int CH = (E + B1 - 1) / B1;
  int lo = blk*CH, hi = min(E, lo + CH);
  for (int i = lo + t; i < hi; i += 256)
    atomicAdd(&hist[dst[i] >> BW_LOG], 1);
  __syncthreads();
  for (int b = t; b < NB; b += 256) blockHist[b*B1 + blk] = hist[b];
}

__global__ __launch_bounds__(B1) void bscan_k(const int* __restrict__ blockHist,
                                              int* __restrict__ wOff, int* __restrict__ bucketCnt){
  __shared__ int s[B1];
  int b = blockIdx.x, t = threadIdx.x;
  int v = blockHist[b*B1 + t];
  s[t] = v; __syncthreads();
  for (int o = 1; o < B1; o <<= 1){
    int u = (t >= o) ? s[t-o] : 0;
    __syncthreads();
    s[t] += u;
    __syncthreads();
  }
  wOff[b*B1 + t] = s[t] - v;
  if (t == B1-1) bucketCnt[b] = s[t];
}

// p1scatter with inline bucket-count scan (NB <= 256)
__global__ __launch_bounds__(256) void p1scatter_k(const int* __restrict__ src, const int* __restrict__ dst,
                                                   int E, int NB,
                                                   const int* __restrict__ bucketCnt,
                                                   const int* __restrict__ wOff,
                                                   int* __restrict__ bucketEdges){
  extern __shared__ int curs[];          // NB ints
  __shared__ int sb[256];
  int blk = blockIdx.x, t = threadIdx.x;
  int v = (t < NB) ? bucketCnt[t] : 0;
  sb[t] = v; __syncthreads();
  for (int o = 1; o < 256; o <<= 1){
    int u = (t >= o) ? sb[t-o] : 0;
    __syncthreads();
    sb[t] += u;
    __syncthreads();
  }
  if (t < NB) curs[t] = (sb[t] - v) + wOff[t*B1 + blk];
  __syncthreads();
  int CH = (E + B1 - 1) / B1;
  int lo = blk*CH, hi = min(E, lo + CH);
  for (int i = lo + t; i < hi; i += 256){
    int dd = dst[i];
    int b = dd >> BW_LOG;
    int pos = atomicAdd(&curs[b], 1);
    bucketEdges[pos] = (src[i] << BW_LOG) | (dd & (BWIDTH-1));
  }
}

// p2 with inline bucket-count scan; also writes off[N]
__global__ __launch_bounds__(BWIDTH) void p2_k(const int* __restrict__ bucketEdges,
                                               const int* __restrict__ bucketCnt, int NB,
                                               int* __restrict__ off, int* __restrict__ csr, int N){
  __shared__ int deg[BWIDTH];
  __shared__ int s[BWIDTH];
  __shared__ int cur[BWIDTH];
  __shared__ int sb[BWIDTH];
  int b = blockIdx.x, t = threadIdx.x;
  int vc = (t < NB) ? bucketCnt[t] : 0;
  sb[t] = vc; __syncthreads();
  for (int o = 1; o < BWIDTH; o <<= 1){
    int u = (t >= o) ? sb[t-o] : 0;
    __syncthreads();
    sb[t] += u;
    __syncthreads();
  }
  int e0 = (b > 0) ? sb[b-1] : 0;
  int e1 = sb[b];
  if (b == 0 && t == 0) off[N] = sb[NB-1];
  deg[t] = 0;
  __syncthreads();
  for (int i = e0 + t; i < e1; i += BWIDTH)
    atomicAdd(&deg[bucketEdges[i] & (BWIDTH-1)], 1);
  __syncthreads();
  int v = deg[t];
  s[t] = v; __syncthreads();
  for (int o = 1; o < BWIDTH; o <<= 1){
    int u = (t >= o) ? s[t-o] : 0;
    __syncthreads();
    s[t] += u;
    __syncthreads();
  }
  int excl = s[t] - v;
  int node = b*BWIDTH + t;
  if (node < N) off[node] = e0 + excl;
  cur[t] = excl;
  __syncthreads();
  for (int i = e0 + t; i < e1; i += BWIDTH){
    int pk = bucketEdges[i];
    int p = atomicAdd(&cur[pk & (BWIDTH-1)], 1);
    csr[e0 + p] = pk >> BW_LOG;
  }
}

// ---------------- W1T: [256][128] fp32 -> [128][256] bf16 ----------------
__global__ __launch_bounds__(256) void wt_k(const float* __restrict__ W, unsigned short* __restrict__ WT){
  int n = blockIdx.x;       // 0..127
  int k = threadIdx.x;      // 0..255
  WT[n*FIN + k] = f2bf(W[(size_t)k*D1 + n]);
}

// ---------------- W2T: [128][40] fp32 -> [48][128] bf16 hi/lo ----------------
__global__ __launch_bounds__(128) void wt2_k(const float* __restrict__ W2,
    unsigned short* __restrict__ W2Th, unsigned short* __restrict__ W2Tl){
  int c = blockIdx.x;       // 0..47
  int k = threadIdx.x;      // 0..127
  float v = (c < D2) ? W2[(size_t)k*D2 + c] : 0.f;
  unsigned short h = f2bf(v);
  W2Th[c*D1 + k] = h;
  W2Tl[c*D1 + k] = f2bf(v - bf2f(h));
}

// ---------------- GEMM1 via MFMA ----------------
__global__ __launch_bounds__(256) void gemm1_mfma(const float* __restrict__ x,
    const unsigned short* __restrict__ W1T,
    const float* __restrict__ attS, const float* __restrict__ attD,
    unsigned short* __restrict__ h1b, float* __restrict__ aS, float* __restrict__ aD, int N){
  int tid = threadIdx.x;
  int w = tid >> 6, lane = tid & 63;
  int lr = lane & 15, lg = lane >> 4;
  int wm = w >> 1, wn = w & 1;
  int m0 = blockIdx.x * 64;

  int rowA[2];
  #pragma unroll
  for (int mi=0;mi<2;mi++){
    int r = m0 + wm*32 + mi*16 + lr;
    rowA[mi] = (r < N) ? r : (N-1);
  }

  f32x4 acc[2][4];
  #pragma unroll
  for (int mi=0;mi<2;mi++)
    #pragma unroll
    for (int ni=0;ni<4;ni++) acc[mi][ni] = (f32x4){0.f,0.f,0.f,0.f};

  #pragma unroll
  for (int ks = 0; ks < 8; ++ks){
    int k0 = ks*32 + lg*8;
    bf16x8 a[2], b[4];
    #pragma unroll
    for (int mi=0;mi<2;mi++){
      const float* px = x + (size_t)rowA[mi]*FIN + k0;
      float4 v0 = *(const float4*)px;
      float4 v1 = *(const float4*)(px+4);
      a[mi] = pack_bf8(v0, v1);
    }
    #pragma unroll
    for (int ni=0;ni<4;ni++){
      int col = wn*64 + ni*16 + lr;
      b[ni] = *(const bf16x8*)(W1T + (size_t)col*FIN + k0);
    }
    #pragma unroll
    for (int mi=0;mi<2;mi++)
      #pragma unroll
      for (int ni=0;ni<4;ni++)
        acc[mi][ni] = __builtin_amdgcn_mfma_f32_16x16x32_bf16(a[mi], b[ni], acc[mi][ni], 0, 0, 0);
  }

  #pragma unroll
  for (int mi=0;mi<2;mi++){
    #pragma unroll
    for (int ni=0;ni<4;ni++){
      int h = wn*4 + ni;
      int col = wn*64 + ni*16 + lr;
      float sS = attS[h*C1 + lr], sD = attD[h*C1 + lr];
      #pragma unroll
      for (int i=0;i<4;i++){
        int row = m0 + wm*32 + mi*16 + 4*lg + i;
        float v = acc[mi][ni][i];
        float pS = v*sS, pD = v*sD;
        pS += __shfl_xor(pS, 1); pD += __shfl_xor(pD, 1);
        pS += __shfl_xor(pS, 2); pD += __shfl_xor(pD, 2);
        pS += __shfl_xor(pS, 4); pD += __shfl_xor(pD, 4);
        pS += __shfl_xor(pS, 8); pD += __shfl_xor(pD, 8);
        if (row < N){
          h1b[(size_t)row*D1 + col] = f2bf(v);
          if (lr == 0){ aS[row*H1 + h] = pS; aD[row*H1 + h] = pD; }
        }
      }
    }
  }
}

// ---------------- GEMM2 via MFMA, bf16x3 split (fp32-grade) ----------------
// Block 256 thr = 4 waves; wave = 32 rows x 48 cols; block = 128 rows.
__global__ __launch_bounds__(256) void gemm2_mfma(const float* __restrict__ x2,
    const unsigned short* __restrict__ W2Th, const unsigned short* __restrict__ W2Tl,
    const float* __restrict__ attS2, const float* __restrict__ attD2,
    float* __restrict__ h2, float* __restrict__ aS2, float* __restrict__ aD2, int N){
  int tid = threadIdx.x;
  int w = tid >> 6, lane = tid & 63;
  int lr = lane & 15, lg = lane >> 4;
  int m0 = blockIdx.x*128 + w*32;

  int rowA[2];
  #pragma unroll
  for (int mi=0;mi<2;mi++){
    int r = m0 + mi*16 + lr;
    rowA[mi] = (r < N) ? r : (N-1);
  }

  f32x4 acc[2][3];
  #pragma unroll
  for (int mi=0;mi<2;mi++)
    #pragma unroll
    for (int ni=0;ni<3;ni++) acc[mi][ni] = (f32x4){0.f,0.f,0.f,0.f};

  #pragma unroll
  for (int ks = 0; ks < 4; ++ks){
    int k0 = ks*32 + lg*8;
    bf16x8 ah[2], al[2], bh[3], bl[3];
    #pragma unroll
    for (int mi=0;mi<2;mi++)
      pack_hilo(x2 + (size_t)rowA[mi]*D1 + k0, ah[mi], al[mi]);
    #pragma unroll
    for (int ni=0;ni<3;ni++){
      int col = ni*16 + lr;
      bh[ni] = *(const bf16x8*)(W2Th + (size_t)col*D1 + k0);
      bl[ni] = *(const bf16x8*)(W2Tl + (size_t)col*D1 + k0);
    }
    #pragma unroll
    for (int mi=0;mi<2;mi++)
      #pragma unroll
      for (int ni=0;ni<3;ni++){
        acc[mi][ni] = __builtin_amdgcn_mfma_f32_16x16x32_bf16(ah[mi], bh[ni], acc[mi][ni], 0, 0, 0);
        acc[mi][ni] = __builtin_amdgcn_mfma_f32_16x16x32_bf16(ah[mi], bl[ni], acc[mi][ni], 0, 0, 0);
        acc[mi][ni] = __builtin_amdgcn_mfma_f32_16x16x32_bf16(al[mi], bh[ni], acc[mi][ni], 0, 0, 0);
      }
  }

  float attSv[3], attDv[3];
  #pragma unroll
  for (int ni=0;ni<3;ni++){
    int col = ni*16 + lr;
    attSv[ni] = (col < D2) ? attS2[col] : 0.f;
    attDv[ni] = (col < D2) ? attD2[col] : 0.f;
  }
  #pragma unroll
  for (int mi=0;mi<2;mi++){
    #pragma unroll
    for (int i=0;i<4;i++){
      int row = m0 + mi*16 + 4*lg + i;
      float pS = 0.f, pD = 0.f;
      #pragma unroll
      for (int ni=0;ni<3;ni++){
        pS += acc[mi][ni][i]*attSv[ni];
        pD += acc[mi][ni][i]*attDv[ni];
      }
      pS += __shfl_xor(pS, 1); pD += __shfl_xor(pD, 1);
      pS += __shfl_xor(pS, 2); pD += __shfl_xor(pD, 2);
      pS += __shfl_xor(pS, 4); pD += __shfl_xor(pD, 4);
      pS += __shfl_xor(pS, 8); pD += __shfl_xor(pD, 8);
      if (row < N){
        #pragma unroll
        for (int ni=0;ni<3;ni++){
          int col = ni*16 + lr;
          if (col < D2) h2[(size_t)row*D2 + col] = acc[mi][ni][i];
        }
        if (lr == 0){ aS2[row] = pS; aD2[row] = pD; }
      }
    }
  }
}

// ---------------- node1: softmax aggregation over bf16 h1, int4 csr + 8-deep gathers ----------------
__global__ __launch_bounds__(64) void node1_k(const unsigned short* __restrict__ h1b,
    const float* __restrict__ aS, const float* __restrict__ aD,
    const int* __restrict__ off, const int* __restrict__ csr,
    const float* __restrict__ b1, float* __restrict__ x2, int N){
  int n = blockIdx.x;
  int lane = threadIdx.x;
  int c = lane*2;                 // channels c, c+1
  int h = lane >> 3;              // head = c/16
  float ad = aD[n*H1+h];
  float p = __expf(lrelu(aS[n*H1+h] + ad));   // self loop
  float d = p;
  unsigned hv = *(const unsigned*)&h1b[(size_t)n*D1 + c];
  float acc0 = p*bf_lo(hv), acc1 = p*bf_hi(hv);
  int i = off[n], e = off[n+1];
  for (; i < e && (i & 3); ++i){
    int s = csr[i];
    float pp = __expf(lrelu(aS[s*H1+h] + ad));
    unsigned vv = *(const unsigned*)&h1b[(size_t)s*D1 + c];
    d += pp; acc0 += pp*bf_lo(vv); acc1 += pp*bf_hi(vv);
  }
  for (; i+8 <= e; i += 8){
    int4 ca = *(const int4*)&csr[i];
    int4 cb = *(const int4*)&csr[i+4];
    int s[8] = {ca.x,ca.y,ca.z,ca.w,cb.x,cb.y,cb.z,cb.w};
    float a[8]; unsigned v[8];
    #pragma unroll
    for (int u=0;u<8;u++) a[u] = aS[s[u]*H1+h];
    #pragma unroll
    for (int u=0;u<8;u++) v[u] = *(const unsigned*)&h1b[(size_t)s[u]*D1 + c];
    #pragma unroll
    for (int u=0;u<8;u++){
      float pp = __expf(lrelu(a[u]+ad));
      d += pp; acc0 += pp*bf_lo(v[u]); acc1 += pp*bf_hi(v[u]);
    }
  }
  for (; i < e; ++i){
    int s = csr[i];
    float pp = __expf(lrelu(aS[s*H1+h] + ad));
    unsigned vv = *(const unsigned*)&h1b[(size_t)s*D1 + c];
    d += pp; acc0 += pp*bf_lo(vv); acc1 += pp*bf_hi(vv);
  }
  float inv = 1.f/d;
  float o0 = acc0*inv + b1[c];
  float o1 = acc1*inv + b1[c+1];
  x2[(size_t)n*D1+c]   = elu(o0);
  x2[(size_t)n*D1+c+1] = elu(o1);
}

// ---------------- node2: softmax aggregation, int4 csr + 8-deep gathers ----------------
__global__ __launch_bounds__(64) void node2_k(const float* __restrict__ h2,
    const float* __restrict__ aS2, const float* __restrict__ aD2,
    const int* __restrict__ off, const int* __restrict__ csr,
    const float* __restrict__ b2, float* __restrict__ out, int N){
  int n = blockIdx.x;
  int lane = threadIdx.x;
  bool act = lane < 20;
  int c = lane*2;
  float ad = aD2[n];
  float ps = __expf(lrelu(aS2[n] + ad));   // self loop
  float d = ps;
  float acc0 = 0.f, acc1 = 0.f;
  if (act){ float2 v = *(const float2*)&h2[(size_t)n*D2 + c]; acc0 = ps*v.x; acc1 = ps*v.y; }
  int i = off[n], e = off[n+1];
  for (; i < e && (i & 3); ++i){
    int s = csr[i];
    float pp = __expf(lrelu(aS2[s] + ad));
    d += pp;
    if (act){
      float2 vv = *(const float2*)&h2[(size_t)s*D2 + c];
      acc0 += pp*vv.x; acc1 += pp*vv.y;
    }
  }
  for (; i+8 <= e; i += 8){
    int4 ca = *(const int4*)&csr[i];
    int4 cb = *(const int4*)&csr[i+4];
    int s[8] = {ca.x,ca.y,ca.z,ca.w,cb.x,cb.y,cb.z,cb.w};
    float a[8]; float2 v[8];
    #pragma unroll
    for (int u=0;u<8;u++) a[u] = aS2[s[u]];
    if (act){
      #pragma unroll
      for (int u=0;u<8;u++) v[u] = *(const float2*)&h2[(size_t)s[u]*D2 + c];
    } else {
      #pragma unroll
      for (int u=0;u<8;u++) v[u] = make_float2(0.f,0.f);
    }
    #pragma unroll
    for (int u=0;u<8;u++){
      float pp = __expf(lrelu(a[u]+ad));
      d += pp; acc0 += pp*v[u].x; acc1 += pp*v[u].y;
    }
  }
  for (; i < e; ++i){
    int s = csr[i];
    float pp = __expf(lrelu(aS2[s] + ad));
    d += pp;
    if (act){
      float2 vv = *(const float2*)&h2[(size_t)s*D2 + c];
      acc0 += pp*vv.x; acc1 += pp*vv.y;
    }
  }
  if (act){
    float inv = 1.f/d;
    out[(size_t)n*D2 + c]     = acc0*inv + b2[c];
    out[(size_t)n*D2 + c + 1] = acc1*inv + b2[c+1];
  }
}

extern "C" void kernel_launch(void* const* d_in, const int* in_sizes, int n_in,
                              void* d_out, int out_size, void* d_ws, size_t ws_size,
                              hipStream_t stream){
  const float* x     = (const float*)d_in[0];
  const int*   ei    = (const int*)d_in[1];
  const float* W1    = (const float*)d_in[2];
  const float* attS1 = (const float*)d_in[3];
  const float* attD1 = (const float*)d_in[4];
  const float* b1    = (const float*)d_in[5];
  const float* W2    = (const float*)d_in[6];
  const float* attS2 = (const float*)d_in[7];
  const float* attD2 = (const float*)d_in[8];
  const float* b2    = (const float*)d_in[9];
  float* out = (float*)d_out;

  int N = in_sizes[0] / FIN;   // 50000
  int E = in_sizes[1] / 2;     // 1600000
  const int* src = ei;
  const int* dst = ei + E;
  int NB = (N + BWIDTH - 1) >> BW_LOG;    // 98

  char* ws = (char*)d_ws;
  size_t o = 0;
  auto alloc = [&](size_t bytes) -> void* {
    void* p = ws + o;
    o += (bytes + 255) & ~size_t(255);
    return p;
  };
  unsigned short* h1b = (unsigned short*)alloc((size_t)N*D1*sizeof(unsigned short));
  float* x2    = (float*)alloc((size_t)N*D1*sizeof(float));
  float* h2    = (float*)alloc((size_t)N*D2*sizeof(float));
  float* aS1   = (float*)alloc((size_t)N*H1*sizeof(float));
  float* aD1   = (float*)alloc((size_t)N*H1*sizeof(float));
  float* aS2   = (float*)alloc((size_t)N*sizeof(float));
  float* aD2   = (float*)alloc((size_t)N*sizeof(float));
  int*   off   = (int*)alloc((size_t)(N+1)*sizeof(int));
  int*   csr   = (int*)alloc((size_t)E*sizeof(int));
  int*   blockHist   = (int*)alloc((size_t)NB*B1*sizeof(int));
  int*   wOff        = (int*)alloc((size_t)NB*B1*sizeof(int));
  int*   bucketCnt   = (int*)alloc((size_t)NB*sizeof(int));
  int*   bucketEdges = (int*)alloc((size_t)E*sizeof(int));
  unsigned short* W1T  = (unsigned short*)alloc((size_t)D1*FIN*sizeof(unsigned short));
  unsigned short* W2Th = (unsigned short*)alloc((size_t)D2P*D1*sizeof(unsigned short));
  unsigned short* W2Tl = (unsigned short*)alloc((size_t)D2P*D1*sizeof(unsigned short));

  size_t smNB = (size_t)NB*sizeof(int);
  p1count_k<<<B1, 256, smNB, stream>>>(dst, E, NB, blockHist);
  bscan_k<<<NB, B1, 0, stream>>>(blockHist, wOff, bucketCnt);
  p1scatter_k<<<B1, 256, smNB, stream>>>(src, dst, E, NB, bucketCnt, wOff, bucketEdges);
  p2_k<<<NB, BWIDTH, 0, stream>>>(bucketEdges, bucketCnt, NB, off, csr, N);
  wt_k<<<D1, 256, 0, stream>>>(W1, W1T);
  wt2_k<<<D2P, 128, 0, stream>>>(W2, W2Th, W2Tl);
  gemm1_mfma<<<(N+63)/64, 256, 0, stream>>>(x, W1T, attS1, attD1, h1b, aS1, aD1, N);
  node1_k<<<N, 64, 0, stream>>>(h1b, aS1, aD1, off, csr, b1, x2, N);
  gemm2_mfma<<<(N+127)/128, 256, 0, stream>>>(x2, W2Th, W2Tl, attS2, attD2, h2, aS2, aD2, N);
  node2_k<<<N, 64, 0, stream>>>(h2, aS2, aD2, off, csr, b2, out, N);
}

// Round 9
// 223.070 us; speedup vs baseline: 3.5415x; 1.0510x over previous
//
#include <hip/hip_runtime.h>

#define FIN 256
#define H1 8
#define C1 16
#define D1 128   // H1*C1
#define D2 40
#define D2P 48

#define BW_LOG 8
#define BWIDTH 256           // nodes per bucket
#define B1 512               // phase-1 blocks

typedef float f32x4 __attribute__((ext_vector_type(4)));
typedef short bf16x8 __attribute__((ext_vector_type(8)));

static __device__ __forceinline__ float lrelu(float x){ return fmaxf(x, 0.2f*x); }
static __device__ __forceinline__ float elu(float x){ return x > 0.f ? x : __expf(x) - 1.f; }
static __device__ __forceinline__ unsigned short f2bf(float f){      // RNE bf16
  unsigned u = __float_as_uint(f);
  return (unsigned short)((u + 0x7fffu + ((u >> 16) & 1u)) >> 16);
}
static __device__ __forceinline__ float bf_lo(unsigned v){ return __uint_as_float(v << 16); }
static __device__ __forceinline__ float bf_hi(unsigned v){ return __uint_as_float(v & 0xffff0000u); }
static __device__ __forceinline__ bf16x8 pack_bf8(float4 a, float4 b){
  bf16x8 r;
  r[0]=(short)f2bf(a.x); r[1]=(short)f2bf(a.y); r[2]=(short)f2bf(a.z); r[3]=(short)f2bf(a.w);
  r[4]=(short)f2bf(b.x); r[5]=(short)f2bf(b.y); r[6]=(short)f2bf(b.z); r[7]=(short)f2bf(b.w);
  return r;
}

// ---------------- CSR build: deterministic bucket sort ----------------
__global__ __launch_bounds__(256) void p1count_k(const int* __restrict__ dst, int E, int NB,
                                                 int* __restrict__ blockHist){
  extern __shared__ int hist[];
  int blk = blockIdx.x, t = threadIdx.x;
  for (int i = t; i < NB; i += 256) hist[i] = 0;
  __syncthreads();
  int CH = (E + B1 - 1) / B1;
  int lo = blk*CH, hi = min(E, lo + CH);
  for (int i = lo + t; i < hi; i += 256)
    atomicAdd(&hist[dst[i] >> BW_LOG], 1);
  __syncthreads();
  for (int b = t; b < NB; b += 256) blockHist[b*B1 + blk] = hist[b];
}

__global__ __launch_bounds__(B1) void bscan_k(const int* __restrict__ blockHist,
                                              int* __restrict__ wOff, int* __restrict__ bucketCnt){
  __shared__ int s[B1];
  int b = blockIdx.x, t = threadIdx.x;
  int v = blockHist[b*B1 + t];
  s[t] = v; __syncthreads();
  for (int o = 1; o < B1; o <<= 1){
    int u = (t >= o) ? s[t-o] : 0;
    __syncthreads();
    s[t] += u;
    __syncthreads();
  }
  wOff[b*B1 + t] = s[t] - v;
  if (t == B1-1) bucketCnt[b] = s[t];
}

// p1scatter with inline bucket-count scan (NB <= 256)
__global__ __launch_bounds__(256) void p1scatter_k(const int* __restrict__ src, const int* __restrict__ dst,
                                                   int E, int NB,
                                                   const int* __restrict__ bucketCnt,
                                                   const int* __restrict__ wOff,
                                                   int* __restrict__ bucketEdges){
  extern __shared__ int curs[];          // NB ints
  __shared__ int sb[256];
  int blk = blockIdx.x, t = threadIdx.x;
  int v = (t < NB) ? bucketCnt[t] : 0;
  sb[t] = v; __syncthreads();
  for (int o = 1; o < 256; o <<= 1){
    int u = (t >= o) ? sb[t-o] : 0;
    __syncthreads();
    sb[t] += u;
    __syncthreads();
  }
  if (t < NB) curs[t] = (sb[t] - v) + wOff[t*B1 + blk];
  __syncthreads();
  int CH = (E + B1 - 1) / B1;
  int lo = blk*CH, hi = min(E, lo + CH);
  for (int i = lo + t; i < hi; i += 256){
    int dd = dst[i];
    int b = dd >> BW_LOG;
    int pos = atomicAdd(&curs[b], 1);
    bucketEdges[pos] = (src[i] << BW_LOG) | (dd & (BWIDTH-1));
  }
}

// p2 with inline bucket-count scan; also writes off[N]
__global__ __launch_bounds__(BWIDTH) void p2_k(const int* __restrict__ bucketEdges,
                                               const int* __restrict__ bucketCnt, int NB,
                                               int* __restrict__ off, int* __restrict__ csr, int N){
  __shared__ int deg[BWIDTH];
  __shared__ int s[BWIDTH];
  __shared__ int cur[BWIDTH];
  __shared__ int sb[BWIDTH];
  int b = blockIdx.x, t = threadIdx.x;
  int vc = (t < NB) ? bucketCnt[t] : 0;
  sb[t] = vc; __syncthreads();
  for (int o = 1; o < BWIDTH; o <<= 1){
    int u = (t >= o) ? sb[t-o] : 0;
    __syncthreads();
    sb[t] += u;
    __syncthreads();
  }
  int e0 = (b > 0) ? sb[b-1] : 0;
  int e1 = sb[b];
  if (b == 0 && t == 0) off[N] = sb[NB-1];
  deg[t] = 0;
  __syncthreads();
  for (int i = e0 + t; i < e1; i += BWIDTH)
    atomicAdd(&deg[bucketEdges[i] & (BWIDTH-1)], 1);
  __syncthreads();
  int v = deg[t];
  s[t] = v; __syncthreads();
  for (int o = 1; o < BWIDTH; o <<= 1){
    int u = (t >= o) ? s[t-o] : 0;
    __syncthreads();
    s[t] += u;
    __syncthreads();
  }
  int excl = s[t] - v;
  int node = b*BWIDTH + t;
  if (node < N) off[node] = e0 + excl;
  cur[t] = excl;
  __syncthreads();
  for (int i = e0 + t; i < e1; i += BWIDTH){
    int pk = bucketEdges[i];
    int p = atomicAdd(&cur[pk & (BWIDTH-1)], 1);
    csr[e0 + p] = pk >> BW_LOG;
  }
}

// ---------------- W1T: [256][128] fp32 -> [128][256] bf16 ----------------
__global__ __launch_bounds__(256) void wt_k(const float* __restrict__ W, unsigned short* __restrict__ WT){
  int n = blockIdx.x;       // 0..127
  int k = threadIdx.x;      // 0..255
  WT[n*FIN + k] = f2bf(W[(size_t)k*D1 + n]);
}

// ---------------- W2T: [128][40] fp32 -> [48][128] bf16 ----------------
__global__ __launch_bounds__(128) void wt2_k(const float* __restrict__ W2, unsigned short* __restrict__ W2T){
  int c = blockIdx.x;       // 0..47
  int k = threadIdx.x;      // 0..127
  float v = (c < D2) ? W2[(size_t)k*D2 + c] : 0.f;
  W2T[c*D1 + k] = f2bf(v);
}

// ---------------- GEMM1 via MFMA ----------------
__global__ __launch_bounds__(256) void gemm1_mfma(const float* __restrict__ x,
    const unsigned short* __restrict__ W1T,
    const float* __restrict__ attS, const float* __restrict__ attD,
    unsigned short* __restrict__ h1b, float* __restrict__ aS, float* __restrict__ aD, int N){
  int tid = threadIdx.x;
  int w = tid >> 6, lane = tid & 63;
  int lr = lane & 15, lg = lane >> 4;
  int wm = w >> 1, wn = w & 1;
  int m0 = blockIdx.x * 64;

  int rowA[2];
  #pragma unroll
  for (int mi=0;mi<2;mi++){
    int r = m0 + wm*32 + mi*16 + lr;
    rowA[mi] = (r < N) ? r : (N-1);
  }

  f32x4 acc[2][4];
  #pragma unroll
  for (int mi=0;mi<2;mi++)
    #pragma unroll
    for (int ni=0;ni<4;ni++) acc[mi][ni] = (f32x4){0.f,0.f,0.f,0.f};

  #pragma unroll
  for (int ks = 0; ks < 8; ++ks){
    int k0 = ks*32 + lg*8;
    bf16x8 a[2], b[4];
    #pragma unroll
    for (int mi=0;mi<2;mi++){
      const float* px = x + (size_t)rowA[mi]*FIN + k0;
      float4 v0 = *(const float4*)px;
      float4 v1 = *(const float4*)(px+4);
      a[mi] = pack_bf8(v0, v1);
    }
    #pragma unroll
    for (int ni=0;ni<4;ni++){
      int col = wn*64 + ni*16 + lr;
      b[ni] = *(const bf16x8*)(W1T + (size_t)col*FIN + k0);
    }
    #pragma unroll
    for (int mi=0;mi<2;mi++)
      #pragma unroll
      for (int ni=0;ni<4;ni++)
        acc[mi][ni] = __builtin_amdgcn_mfma_f32_16x16x32_bf16(a[mi], b[ni], acc[mi][ni], 0, 0, 0);
  }

  #pragma unroll
  for (int mi=0;mi<2;mi++){
    #pragma unroll
    for (int ni=0;ni<4;ni++){
      int h = wn*4 + ni;
      int col = wn*64 + ni*16 + lr;
      float sS = attS[h*C1 + lr], sD = attD[h*C1 + lr];
      #pragma unroll
      for (int i=0;i<4;i++){
        int row = m0 + wm*32 + mi*16 + 4*lg + i;
        float v = acc[mi][ni][i];
        float pS = v*sS, pD = v*sD;
        pS += __shfl_xor(pS, 1); pD += __shfl_xor(pD, 1);
        pS += __shfl_xor(pS, 2); pD += __shfl_xor(pD, 2);
        pS += __shfl_xor(pS, 4); pD += __shfl_xor(pD, 4);
        pS += __shfl_xor(pS, 8); pD += __shfl_xor(pD, 8);
        if (row < N){
          h1b[(size_t)row*D1 + col] = f2bf(v);
          if (lr == 0){ aS[row*H1 + h] = pS; aD[row*H1 + h] = pD; }
        }
      }
    }
  }
}

// ---------------- GEMM2 via MFMA, pure bf16 (x2b bf16 in, h2b bf16 out) ----------------
// Block 256 thr = 4 waves; wave = 32 rows x 48 cols; block = 128 rows.
__global__ __launch_bounds__(256) void gemm2_mfma(const unsigned short* __restrict__ x2b,
    const unsigned short* __restrict__ W2T,
    const float* __restrict__ attS2, const float* __restrict__ attD2,
    unsigned short* __restrict__ h2b, float* __restrict__ aS2, float* __restrict__ aD2, int N){
  int tid = threadIdx.x;
  int w = tid >> 6, lane = tid & 63;
  int lr = lane & 15, lg = lane >> 4;
  int m0 = blockIdx.x*128 + w*32;

  int rowA[2];
  #pragma unroll
  for (int mi=0;mi<2;mi++){
    int r = m0 + mi*16 + lr;
    rowA[mi] = (r < N) ? r : (N-1);
  }

  f32x4 acc[2][3];
  #pragma unroll
  for (int mi=0;mi<2;mi++)
    #pragma unroll
    for (int ni=0;ni<3;ni++) acc[mi][ni] = (f32x4){0.f,0.f,0.f,0.f};

  #pragma unroll
  for (int ks = 0; ks < 4; ++ks){
    int k0 = ks*32 + lg*8;
    bf16x8 a[2], b[3];
    #pragma unroll
    for (int mi=0;mi<2;mi++)
      a[mi] = *(const bf16x8*)(x2b + (size_t)rowA[mi]*D1 + k0);
    #pragma unroll
    for (int ni=0;ni<3;ni++){
      int col = ni*16 + lr;
      b[ni] = *(const bf16x8*)(W2T + (size_t)col*D1 + k0);
    }
    #pragma unroll
    for (int mi=0;mi<2;mi++)
      #pragma unroll
      for (int ni=0;ni<3;ni++)
        acc[mi][ni] = __builtin_amdgcn_mfma_f32_16x16x32_bf16(a[mi], b[ni], acc[mi][ni], 0, 0, 0);
  }

  float attSv[3], attDv[3];
  #pragma unroll
  for (int ni=0;ni<3;ni++){
    int col = ni*16 + lr;
    attSv[ni] = (col < D2) ? attS2[col] : 0.f;
    attDv[ni] = (col < D2) ? attD2[col] : 0.f;
  }
  #pragma unroll
  for (int mi=0;mi<2;mi++){
    #pragma unroll
    for (int i=0;i<4;i++){
      int row = m0 + mi*16 + 4*lg + i;
      float pS = 0.f, pD = 0.f;
      #pragma unroll
      for (int ni=0;ni<3;ni++){
        pS += acc[mi][ni][i]*attSv[ni];
        pD += acc[mi][ni][i]*attDv[ni];
      }
      pS += __shfl_xor(pS, 1); pD += __shfl_xor(pD, 1);
      pS += __shfl_xor(pS, 2); pD += __shfl_xor(pD, 2);
      pS += __shfl_xor(pS, 4); pD += __shfl_xor(pD, 4);
      pS += __shfl_xor(pS, 8); pD += __shfl_xor(pD, 8);
      if (row < N){
        #pragma unroll
        for (int ni=0;ni<3;ni++){
          int col = ni*16 + lr;
          if (col < D2) h2b[(size_t)row*D2 + col] = f2bf(acc[mi][ni][i]);
        }
        if (lr == 0){ aS2[row] = pS; aD2[row] = pD; }
      }
    }
  }
}

// ---------------- node1: softmax aggregation over bf16 h1 -> bf16 x2 ----------------
__global__ __launch_bounds__(64) void node1_k(const unsigned short* __restrict__ h1b,
    const float* __restrict__ aS, const float* __restrict__ aD,
    const int* __restrict__ off, const int* __restrict__ csr,
    const float* __restrict__ b1, unsigned short* __restrict__ x2b, int N){
  int n = blockIdx.x;
  int lane = threadIdx.x;
  int c = lane*2;                 // channels c, c+1
  int h = lane >> 3;              // head = c/16
  float ad = aD[n*H1+h];
  float p = __expf(lrelu(aS[n*H1+h] + ad));   // self loop
  float d = p;
  unsigned hv = *(const unsigned*)&h1b[(size_t)n*D1 + c];
  float acc0 = p*bf_lo(hv), acc1 = p*bf_hi(hv);
  int i = off[n], e = off[n+1];
  for (; i < e && (i & 3); ++i){
    int s = csr[i];
    float pp = __expf(lrelu(aS[s*H1+h] + ad));
    unsigned vv = *(const unsigned*)&h1b[(size_t)s*D1 + c];
    d += pp; acc0 += pp*bf_lo(vv); acc1 += pp*bf_hi(vv);
  }
  for (; i+8 <= e; i += 8){
    int4 ca = *(const int4*)&csr[i];
    int4 cb = *(const int4*)&csr[i+4];
    int s[8] = {ca.x,ca.y,ca.z,ca.w,cb.x,cb.y,cb.z,cb.w};
    float a[8]; unsigned v[8];
    #pragma unroll
    for (int u=0;u<8;u++) a[u] = aS[s[u]*H1+h];
    #pragma unroll
    for (int u=0;u<8;u++) v[u] = *(const unsigned*)&h1b[(size_t)s[u]*D1 + c];
    #pragma unroll
    for (int u=0;u<8;u++){
      float pp = __expf(lrelu(a[u]+ad));
      d += pp; acc0 += pp*bf_lo(v[u]); acc1 += pp*bf_hi(v[u]);
    }
  }
  for (; i < e; ++i){
    int s = csr[i];
    float pp = __expf(lrelu(aS[s*H1+h] + ad));
    unsigned vv = *(const unsigned*)&h1b[(size_t)s*D1 + c];
    d += pp; acc0 += pp*bf_lo(vv); acc1 += pp*bf_hi(vv);
  }
  float inv = 1.f/d;
  float o0 = elu(acc0*inv + b1[c]);
  float o1 = elu(acc1*inv + b1[c+1]);
  unsigned pk = (unsigned)f2bf(o0) | ((unsigned)f2bf(o1) << 16);
  *(unsigned*)&x2b[(size_t)n*D1 + c] = pk;
}

// ---------------- node2: softmax aggregation over bf16 h2 ----------------
__global__ __launch_bounds__(64) void node2_k(const unsigned short* __restrict__ h2b,
    const float* __restrict__ aS2, const float* __restrict__ aD2,
    const int* __restrict__ off, const int* __restrict__ csr,
    const float* __restrict__ b2, float* __restrict__ out, int N){
  int n = blockIdx.x;
  int lane = threadIdx.x;
  bool act = lane < 20;
  int c = lane*2;
  float ad = aD2[n];
  float ps = __expf(lrelu(aS2[n] + ad));   // self loop
  float d = ps;
  float acc0 = 0.f, acc1 = 0.f;
  if (act){
    unsigned v = *(const unsigned*)&h2b[(size_t)n*D2 + c];
    acc0 = ps*bf_lo(v); acc1 = ps*bf_hi(v);
  }
  int i = off[n], e = off[n+1];
  for (; i < e && (i & 3); ++i){
    int s = csr[i];
    float pp = __expf(lrelu(aS2[s] + ad));
    d += pp;
    if (act){
      unsigned vv = *(const unsigned*)&h2b[(size_t)s*D2 + c];
      acc0 += pp*bf_lo(vv); acc1 += pp*bf_hi(vv);
    }
  }
  for (; i+8 <= e; i += 8){
    int4 ca = *(const int4*)&csr[i];
    int4 cb = *(const int4*)&csr[i+4];
    int s[8] = {ca.x,ca.y,ca.z,ca.w,cb.x,cb.y,cb.z,cb.w};
    float a[8]; unsigned v[8];
    #pragma unroll
    for (int u=0;u<8;u++) a[u] = aS2[s[u]];
    if (act){
      #pragma unroll
      for (int u=0;u<8;u++) v[u] = *(const unsigned*)&h2b[(size_t)s[u]*D2 + c];
    } else {
      #pragma unroll
      for (int u=0;u<8;u++) v[u] = 0u;
    }
    #pragma unroll
    for (int u=0;u<8;u++){
      float pp = __expf(lrelu(a[u]+ad));
      d += pp; acc0 += pp*bf_lo(v[u]); acc1 += pp*bf_hi(v[u]);
    }
  }
  for (; i < e; ++i){
    int s = csr[i];
    float pp = __expf(lrelu(aS2[s] + ad));
    d += pp;
    if (act){
      unsigned vv = *(const unsigned*)&h2b[(size_t)s*D2 + c];
      acc0 += pp*bf_lo(vv); acc1 += pp*bf_hi(vv);
    }
  }
  if (act){
    float inv = 1.f/d;
    out[(size_t)n*D2 + c]     = acc0*inv + b2[c];
    out[(size_t)n*D2 + c + 1] = acc1*inv + b2[c+1];
  }
}

extern "C" void kernel_launch(void* const* d_in, const int* in_sizes, int n_in,
                              void* d_out, int out_size, void* d_ws, size_t ws_size,
                              hipStream_t stream){
  const float* x     = (const float*)d_in[0];
  const int*   ei    = (const int*)d_in[1];
  const float* W1    = (const float*)d_in[2];
  const float* attS1 = (const float*)d_in[3];
  const float* attD1 = (const float*)d_in[4];
  const float* b1    = (const float*)d_in[5];
  const float* W2    = (const float*)d_in[6];
  const float* attS2 = (const float*)d_in[7];
  const float* attD2 = (const float*)d_in[8];
  const float* b2    = (const float*)d_in[9];
  float* out = (float*)d_out;

  int N = in_sizes[0] / FIN;   // 50000
  int E = in_sizes[1] / 2;     // 1600000
  const int* src = ei;
  const int* dst = ei + E;
  int NB = (N + BWIDTH - 1) >> BW_LOG;    // 196

  char* ws = (char*)d_ws;
  size_t o = 0;
  auto alloc = [&](size_t bytes) -> void* {
    void* p = ws + o;
    o += (bytes + 255) & ~size_t(255);
    return p;
  };
  unsigned short* h1b = (unsigned short*)alloc((size_t)N*D1*sizeof(unsigned short));
  unsigned short* x2b = (unsigned short*)alloc((size_t)N*D1*sizeof(unsigned short));
  unsigned short* h2b = (unsigned short*)alloc((size_t)N*D2*sizeof(unsigned short));
  float* aS1   = (float*)alloc((size_t)N*H1*sizeof(float));
  float* aD1   = (float*)alloc((size_t)N*H1*sizeof(float));
  float* aS2   = (float*)alloc((size_t)N*sizeof(float));
  float* aD2   = (float*)alloc((size_t)N*sizeof(float));
  int*   off   = (int*)alloc((size_t)(N+1)*sizeof(int));
  int*   csr   = (int*)alloc((size_t)E*sizeof(int));
  int*   blockHist   = (int*)alloc((size_t)NB*B1*sizeof(int));
  int*   wOff        = (int*)alloc((size_t)NB*B1*sizeof(int));
  int*   bucketCnt   = (int*)alloc((size_t)NB*sizeof(int));
  int*   bucketEdges = (int*)alloc((size_t)E*sizeof(int));
  unsigned short* W1T = (unsigned short*)alloc((size_t)D1*FIN*sizeof(unsigned short));
  unsigned short* W2T = (unsigned short*)alloc((size_t)D2P*D1*sizeof(unsigned short));

  size_t smNB = (size_t)NB*sizeof(int);
  p1count_k<<<B1, 256, smNB, stream>>>(dst, E, NB, blockHist);
  bscan_k<<<NB, B1, 0, stream>>>(blockHist, wOff, bucketCnt);
  p1scatter_k<<<B1, 256, smNB, stream>>>(src, dst, E, NB, bucketCnt, wOff, bucketEdges);
  p2_k<<<NB, BWIDTH, 0, stream>>>(bucketEdges, bucketCnt, NB, off, csr, N);
  wt_k<<<D1, 256, 0, stream>>>(W1, W1T);
  wt2_k<<<D2P, 128, 0, stream>>>(W2, W2T);
  gemm1_mfma<<<(N+63)/64, 256, 0, stream>>>(x, W1T, attS1, attD1, h1b, aS1, aD1, N);
  node1_k<<<N, 64, 0, stream>>>(h1b, aS1, aD1, off, csr, b1, x2b, N);
  gemm2_mfma<<<(N+127)/128, 256, 0, stream>>>(x2b, W2T, attS2, attD2, h2b, aS2, aD2, N);
  node2_k<<<N, 64, 0, stream>>>(h2b, aS2, aD2, off, csr, b2, out, N);
}